// Round 7
// baseline (664.696 us; speedup 1.0000x reference)
//
#include <hip/hip_runtime.h>
#include <math.h>

static constexpr int L_SEQ  = 3136;
static constexpr int NBATCH = 8;
static constexpr int CDIM   = 384;
static constexpr int DIN    = 768;
static constexpr int NHM    = 12;
static constexpr int HDM    = 64;
static constexpr int DPROJ  = 1676;   // 2*768 + 2*64 + 12
static constexpr int CONVD  = 896;    // 768 + 128
static constexpr int NROWS  = NBATCH * L_SEQ; // 25088
static constexpr int NHA    = 12;
static constexpr int NCH    = 49;     // chunks per sequence
static constexpr int CHT    = 64;     // tokens per chunk (49*64 = 3136)
static constexpr int CTK    = 28;     // tokens per conv thread (3136/28 = 112)
static constexpr int ZXLD   = 1024;   // combined xBC+dt output stride (908 padded)

typedef __attribute__((ext_vector_type(8))) short short8;
typedef __attribute__((ext_vector_type(8))) unsigned short ushort8;
typedef __attribute__((ext_vector_type(4))) float f32x4;
typedef const unsigned int __attribute__((address_space(1)))* gua_t;
typedef unsigned int __attribute__((address_space(3)))* lua_t;

__device__ __forceinline__ float siluf(float x) { return x / (1.f + __expf(-x)); }
__device__ __forceinline__ unsigned short f2bf(float f) {
  unsigned int u = __float_as_uint(f);
  u += 0x7fff + ((u >> 16) & 1);
  return (unsigned short)(u >> 16);
}
__device__ __forceinline__ float bf2f(unsigned short h) {
  return __uint_as_float(((unsigned int)h) << 16);
}
// GELU via A&S 7.1.25 3-term erf (|err|<=2.5e-5, far below bf16 ulp):
// gelu(v) = 0.5 v + 0.5|v| * erf(|v|/sqrt2)
__device__ __forceinline__ float geluf(float v) {
  float ax = fabsf(v) * 0.70710678118654752f;
  float t = __builtin_amdgcn_rcpf(fmaf(0.47047f, ax, 1.f));
  float p = t * fmaf(t, fmaf(t, 0.7478556f, -0.0958798f), 0.3480242f);
  float e = __expf(-ax * ax);
  float r = 1.f - p * e;
  float h = 0.5f * v;
  return fmaf(fabsf(h), r, h);
}
__device__ __forceinline__ unsigned int pk_bf16(float lo, float hi) {
  unsigned int d;
  asm("v_cvt_pk_bf16_f32 %0, %1, %2" : "=v"(d) : "v"(lo), "v"(hi));
  return d;
}

// ---------------- LayerNorm: one wave per row, C=384, bf16 out ----------------
__global__ __launch_bounds__(256) void ln_kernel(const float* __restrict__ in,
    const float* __restrict__ w, const float* __restrict__ b, unsigned short* __restrict__ out) {
  int wave = threadIdx.x >> 6, lane = threadIdx.x & 63;
  int row = blockIdx.x * 4 + wave;
  if (row >= NROWS) return;
  const float* r = in + (size_t)row * CDIM;
  float2 v[3];
  float s1 = 0.f, s2 = 0.f;
#pragma unroll
  for (int q = 0; q < 3; q++) {
    v[q] = *(const float2*)&r[q * 128 + lane * 2];
    s1 += v[q].x + v[q].y;
    s2 += v[q].x * v[q].x + v[q].y * v[q].y;
  }
#pragma unroll
  for (int o = 32; o > 0; o >>= 1) { s1 += __shfl_xor(s1, o, 64); s2 += __shfl_xor(s2, o, 64); }
  float mu = s1 * (1.f / 384.f);
  float var = s2 * (1.f / 384.f) - mu * mu;
  float rs = rsqrtf(var + 1e-5f);
  unsigned short* o = out + (size_t)row * CDIM;
#pragma unroll
  for (int q = 0; q < 3; q++) {
    int c = q * 128 + lane * 2;
    float2 wv = *(const float2*)&w[c];
    float2 bv = *(const float2*)&b[c];
    float ox = (v[q].x - mu) * rs * wv.x + bv.x;
    float oy = (v[q].y - mu) * rs * wv.y + bv.y;
    *(unsigned int*)&o[c] = pk_bf16(ox, oy);
  }
}

// ---------------- weight convert + transpose: W[K][N] fp32 -> WT[Np][K] bf16 ----------------
__global__ __launch_bounds__(256) void wconv_kernel(const float* __restrict__ W,
    unsigned short* __restrict__ WT, int K, int N, int ldw) {
  __shared__ float tile[32][33];
  int k0 = blockIdx.x * 32, n0 = blockIdx.y * 32;
  int tx = threadIdx.x & 31, ty = threadIdx.x >> 5;
#pragma unroll
  for (int j = 0; j < 4; j++) {
    int k = k0 + ty + j * 8;
    int n = n0 + tx;
    tile[ty + j * 8][tx] = (n < N) ? W[(size_t)k * ldw + n] : 0.f;
  }
  __syncthreads();
#pragma unroll
  for (int j = 0; j < 4; j++) {
    int n = n0 + ty + j * 8;
    int k = k0 + tx;
    WT[(size_t)n * K + k] = f2bf(tile[tx][ty + j * 8]);
  }
}

// ---------------- bf16 MFMA GEMM: 2-buffer 1-barrier pipeline, pointer-increment staging,
// ---------------- slot-XOR LDS swizzle, XCD swizzle, TRANSPOSED acc -> in-lane packed stores
template<int ACT, bool HASBIAS, bool HASRES, bool OUTBF>
__global__ __launch_bounds__(256, 4) void gemm_bf(
    const unsigned short* __restrict__ A, const unsigned short* __restrict__ WT,
    void* __restrict__ Cp, const float* __restrict__ bias,
    const float* __restrict__ res, int ldr,
    int M, int N, int K, int lda, int ldc, int coff)
{
  __shared__ unsigned short SMEM[16384];   // As[2] @0, Ws[2] @8192 (4096 shorts each)
  int t = threadIdx.x;
  // XCD-aware bijective remap (m204)
  int gx = gridDim.x;
  int nwg = gx * gridDim.y;
  int orig = blockIdx.y * gx + blockIdx.x;
  int qq = nwg >> 3, rr = nwg & 7;
  int xcd = orig & 7, seq = orig >> 3;
  int wgid = (xcd < rr ? xcd * (qq + 1) : rr * (qq + 1) + (xcd - rr) * qq) + seq;
  int m0 = (wgid / gx) * 128, n0 = (wgid % gx) * 128;

  int lane = t & 63, w = t >> 6;
  int wr = (w >> 1) * 64, wc = (w & 1) * 64;
  int fl = lane & 15, kq = lane >> 4;
  int so = (kq ^ ((lane >> 1) & 3)) * 8;   // swizzled 16B slot for ds_read

  // staging: thread t owns chunk t (rows 0..63) and chunk 256+t (rows 64..127); advance 32 elems/iter
  int srow = t >> 2, sq = t & 3;
  int q0 = sq ^ ((srow >> 1) & 3);
  const unsigned short* pA0 = A  + (size_t)(m0 + srow) * lda + q0 * 8;
  const unsigned short* pA1 = A  + (size_t)(m0 + 64 + srow) * lda + q0 * 8;
  const unsigned short* pW0 = WT + (size_t)(n0 + srow) * K + q0 * 8;
  const unsigned short* pW1 = WT + (size_t)(n0 + 64 + srow) * K + q0 * 8;

  f32x4 acc[4][4];     // acc[mi][ni]: rows = n (reg), cols = m (lane)  [transposed output]
#pragma unroll
  for (int i = 0; i < 4; i++)
#pragma unroll
    for (int j = 0; j < 4; j++) acc[i][j] = (f32x4)0.f;

  auto STAGE = [&](int buf) {
    unsigned short* as = SMEM + buf * 4096;
    unsigned short* ws = SMEM + 8192 + buf * 4096;
    __builtin_amdgcn_global_load_lds((gua_t)pA0, (lua_t)as + t * 4, 16, 0, 0);
    __builtin_amdgcn_global_load_lds((gua_t)pA1, (lua_t)(as + 2048) + t * 4, 16, 0, 0);
    __builtin_amdgcn_global_load_lds((gua_t)pW0, (lua_t)ws + t * 4, 16, 0, 0);
    __builtin_amdgcn_global_load_lds((gua_t)pW1, (lua_t)(ws + 2048) + t * 4, 16, 0, 0);
    pA0 += 32; pA1 += 32; pW0 += 32; pW1 += 32;
  };

  int nk = K >> 5;
  STAGE(0);
  asm volatile("s_waitcnt vmcnt(0)" ::: "memory");
  __builtin_amdgcn_s_barrier();
  asm volatile("" ::: "memory");
  __builtin_amdgcn_sched_barrier(0);
  int buf = 0;
  for (int ks = 0; ks < nk; ks++) {
    if (ks + 1 < nk) STAGE(buf ^ 1);
    const unsigned short* as = SMEM + buf * 4096;
    const unsigned short* ws = SMEM + 8192 + buf * 4096;
    short8 af[4], bfr[4];
#pragma unroll
    for (int mi = 0; mi < 4; mi++) af[mi] = *(const short8*)&as[(wr + mi * 16 + fl) * 32 + so];
#pragma unroll
    for (int ni = 0; ni < 4; ni++) bfr[ni] = *(const short8*)&ws[(wc + ni * 16 + fl) * 32 + so];
    // swapped operands: output rows = n (from W frag), cols = m (from A frag)
#pragma unroll
    for (int mi = 0; mi < 4; mi++)
#pragma unroll
      for (int ni = 0; ni < 4; ni++)
        acc[mi][ni] = __builtin_amdgcn_mfma_f32_16x16x32_bf16(bfr[ni], af[mi], acc[mi][ni], 0, 0, 0);
    if (ks + 1 < nk) {
      asm volatile("s_waitcnt vmcnt(0)" ::: "memory");   // next tile fully landed
      __builtin_amdgcn_s_barrier();
      asm volatile("" ::: "memory");
      __builtin_amdgcn_sched_barrier(0);
      buf ^= 1;
    }
  }
  // epilogue: lane holds m = wr+mi*16+fl, n = wc+ni*16+kq*4+r (r = reg 0..3)
  int rbase = kq * 4;
  if (OUTBF) {
    unsigned short* outp = (unsigned short*)Cp + coff;
#pragma unroll
    for (int mi = 0; mi < 4; mi++) {
      int m = m0 + wr + mi * 16 + fl;
      unsigned short* rowp = outp + (size_t)m * ldc + n0;
#pragma unroll
      for (int ni = 0; ni < 4; ni++) {
        int nb = wc + ni * 16 + rbase;
        float v0 = acc[mi][ni][0], v1 = acc[mi][ni][1];
        float v2 = acc[mi][ni][2], v3 = acc[mi][ni][3];
        if (HASBIAS) {
          float4 bv = *(const float4*)&bias[n0 + nb];
          v0 += bv.x; v1 += bv.y; v2 += bv.z; v3 += bv.w;
        }
        if (ACT == 1) { v0 = geluf(v0); v1 = geluf(v1); v2 = geluf(v2); v3 = geluf(v3); }
        uint2 pk; pk.x = pk_bf16(v0, v1); pk.y = pk_bf16(v2, v3);
        *(uint2*)&rowp[nb] = pk;
      }
    }
  } else {
    float* outp = (float*)Cp + coff;
#pragma unroll
    for (int mi = 0; mi < 4; mi++) {
      int m = m0 + wr + mi * 16 + fl;
      float* rowp = outp + (size_t)m * ldc + n0;
#pragma unroll
      for (int ni = 0; ni < 4; ni++) {
        int nb = wc + ni * 16 + rbase;
        float4 v;
        v.x = acc[mi][ni][0]; v.y = acc[mi][ni][1];
        v.z = acc[mi][ni][2]; v.w = acc[mi][ni][3];
        if (HASBIAS) {
          float4 bv = *(const float4*)&bias[n0 + nb];
          v.x += bv.x; v.y += bv.y; v.z += bv.z; v.w += bv.w;
        }
        if (ACT == 1) { v.x = geluf(v.x); v.y = geluf(v.y); v.z = geluf(v.z); v.w = geluf(v.w); }
        if (HASRES) {
          float4 rv = *(const float4*)&res[(size_t)m * ldr + n0 + nb];
          v.x += rv.x; v.y += rv.y; v.z += rv.z; v.w += rv.w;
        }
        *(float4*)&rowp[nb] = v;
      }
    }
  }
}

// ---------------- dt prep: read bf16 dt slice of combined ZX; DA holds LOG-decay ----------------
__global__ void dtprep_kernel(const unsigned short* __restrict__ ZX, const float* __restrict__ dt_bias,
    const float* __restrict__ A_log, float* __restrict__ DT, float* __restrict__ DA) {
  int idx = blockIdx.x * blockDim.x + threadIdx.x;
  if (idx >= NROWS * NHM) return;
  int h = idx % NHM;
  int row = idx / NHM;
  float v = bf2f(ZX[(size_t)row * ZXLD + 896 + h]) + dt_bias[h];
  float sp = (v > 20.f) ? v : log1pf(expf(v));
  DT[idx] = sp;
  DA[idx] = -expf(A_log[h]) * sp;   // log of decay (<= 0)
}

// ---------------- depthwise causal conv (k=4) + bias + silu; bf16 in/out, reg shift history ----------------
__global__ __launch_bounds__(256) void conv_bf_kernel(const unsigned short* __restrict__ xbc,
    const float* __restrict__ cw, const float* __restrict__ cb, unsigned short* __restrict__ XC,
    int ldin) {
  int t = blockIdx.x * 256 + threadIdx.x;
  int c8 = t % 112;                 // 8-channel group within row (112*8 = 896)
  int rg = t / 112;                 // b * 112 + lchunk
  int b = rg / 112, lc = rg % 112;
  int l0 = lc * CTK;
  int c0 = c8 * 8;
  float w0[8], w1[8], w2[8], w3[8], bq[8];
#pragma unroll
  for (int i = 0; i < 8; i++) {
    bq[i] = cb[c0 + i];
    float4 w4 = *(const float4*)&cw[(c0 + i) * 4];
    w0[i] = w4.x; w1[i] = w4.y; w2[i] = w4.z; w3[i] = w4.w;
  }
  const unsigned short* base = xbc + (size_t)b * L_SEQ * ldin + c0;
  unsigned short* obase = XC + (size_t)b * L_SEQ * CONVD + c0;
  ushort8 h0 = (ushort8)0, h1 = (ushort8)0, h2 = (ushort8)0;
  if (l0 >= 3) {
    h0 = *(const ushort8*)&base[(size_t)(l0 - 3) * ldin];
    h1 = *(const ushort8*)&base[(size_t)(l0 - 2) * ldin];
    h2 = *(const ushort8*)&base[(size_t)(l0 - 1) * ldin];
  }
  for (int i = 0; i < CTK; i++) {
    ushort8 cur = *(const ushort8*)&base[(size_t)(l0 + i) * ldin];
    ushort8 ov;
#pragma unroll
    for (int q = 0; q < 8; q++) {
      float acc = bq[q] + w0[q] * bf2f(h0[q]) + w1[q] * bf2f(h1[q])
                + w2[q] * bf2f(h2[q]) + w3[q] * bf2f(cur[q]);
      ov[q] = f2bf(siluf(acc));
    }
    *(ushort8*)&obase[(size_t)(l0 + i) * CONVD] = ov;
    h0 = h1; h1 = h2; h2 = cur;
  }
}

// ---------------- chunked SSD scan pass 1 (MFMA): G^T[p][n] = sum_j X[j][p] * (B[j][n]*w[j]) ----------------
__global__ __launch_bounds__(256) void mscan1_kernel(const unsigned short* __restrict__ XC,
    const float* __restrict__ dtp, const float* __restrict__ dta,
    float* __restrict__ H, float* __restrict__ QS) {
  __shared__ unsigned short Xt[64 * 72];   // X^T [p][j]
  __shared__ unsigned short Bt[64 * 72];   // (B*w)^T [n][j]
  __shared__ float lcs[64];
  __shared__ float wss[64];
  int ch = blockIdx.x, bh = blockIdx.y;
  int b = bh / NHM, head = bh - b * NHM;
  int t = threadIdx.x;
  int l0 = ch * CHT;
  const unsigned short* xcb = XC + ((size_t)b * L_SEQ + l0) * CONVD;
  if (t < 64) {
    size_t ro = ((size_t)b * L_SEQ + l0 + t) * NHM + head;
    float s = dta[ro];
#pragma unroll
    for (int o = 1; o < 64; o <<= 1) {
      float u = __shfl_up(s, o, 64);
      if (t >= o) s += u;
    }
    float lc63 = __shfl(s, 63, 64);
    lcs[t] = s;
    wss[t] = dtp[ro] * __expf(lc63 - s);
    if (t == 63) QS[bh * NCH + ch] = __expf(s);
  }
  __syncthreads();
#pragma unroll
  for (int it = 0; it < 16; it++) {
    int e = it * 256 + t;
    int j = e >> 6, cc = e & 63;
    const unsigned short* rowp = xcb + (size_t)j * CONVD;
    Xt[cc * 72 + j] = rowp[head * HDM + cc];
    Bt[cc * 72 + j] = f2bf(bf2f(rowp[768 + cc]) * wss[j]);
  }
  __syncthreads();
  int lane = t & 63, w = t >> 6;
  int wr = (w >> 1) * 32, wc = (w & 1) * 32;
  int fl = lane & 15, kq = lane >> 4;
  f32x4 acc[2][2];
#pragma unroll
  for (int i = 0; i < 2; i++)
#pragma unroll
    for (int j = 0; j < 2; j++) acc[i][j] = (f32x4)0.f;
#pragma unroll
  for (int kk = 0; kk < 2; kk++) {
    short8 af[2], bfr[2];
#pragma unroll
    for (int mi = 0; mi < 2; mi++)
      af[mi] = *(const short8*)&Xt[(wr + mi * 16 + fl) * 72 + kk * 32 + kq * 8];
#pragma unroll
    for (int ni = 0; ni < 2; ni++)
      bfr[ni] = *(const short8*)&Bt[(wc + ni * 16 + fl) * 72 + kk * 32 + kq * 8];
#pragma unroll
    for (int mi = 0; mi < 2; mi++)
#pragma unroll
      for (int ni = 0; ni < 2; ni++)
        acc[mi][ni] = __builtin_amdgcn_mfma_f32_16x16x32_bf16(af[mi], bfr[ni], acc[mi][ni], 0, 0, 0);
  }
  float* Hp = H + ((size_t)bh * NCH + ch) * 4096;
  int rbase = kq * 4, cl = fl;
#pragma unroll
  for (int mi = 0; mi < 2; mi++)
#pragma unroll
    for (int ni = 0; ni < 2; ni++)
#pragma unroll
      for (int r = 0; r < 4; r++)
        Hp[(size_t)(wr + mi * 16 + rbase + r) * 64 + wc + ni * 16 + cl] = acc[mi][ni][r];
}

// ---------------- scan combine (exclusive prefix over chunks) ----------------
__global__ __launch_bounds__(64) void scomb_kernel(float* __restrict__ H,
    const float* __restrict__ QS) {
  int bh = blockIdx.x;
  int e = (blockIdx.y * 64 + threadIdx.x) * 4;
  float4 cur = make_float4(0.f, 0.f, 0.f, 0.f);
  for (int s = 0; s < NCH; s++) {
    float* Hp = H + ((size_t)bh * NCH + s) * 4096 + e;
    float q = QS[bh * NCH + s];
    float4 tmp = *(float4*)Hp;
    *(float4*)Hp = cur;
    cur.x = q * cur.x + tmp.x;
    cur.y = q * cur.y + tmp.y;
    cur.z = q * cur.z + tmp.z;
    cur.w = q * cur.w + tmp.w;
  }
}

// ---------------- chunked SSD scan pass 2 (MFMA) ----------------
__global__ __launch_bounds__(256) void mscan2_kernel(const unsigned short* __restrict__ XC,
    const float* __restrict__ dtp, const float* __restrict__ dta,
    const float* __restrict__ H, const float* __restrict__ Dp,
    unsigned short* __restrict__ Ybf) {
  __shared__ unsigned short Cs[64 * 72];   // C [i][n] (later scaled by exp(lc[i]))
  __shared__ unsigned short Bs[64 * 72];   // B [j][n]
  __shared__ unsigned short Xt[64 * 72];   // X^T [p][j]
  __shared__ unsigned short Hs[64 * 72];   // Hprev [p][n]
  __shared__ unsigned short Ss[64 * 72];   // S [i][j] masked+scaled
  __shared__ float lcs[64];
  __shared__ float dts[64];
  int ch = blockIdx.x, bh = blockIdx.y;
  int b = bh / NHM, head = bh - b * NHM;
  int t = threadIdx.x;
  int l0 = ch * CHT;
  const unsigned short* xcb = XC + ((size_t)b * L_SEQ + l0) * CONVD;
  const float* Hg = H + ((size_t)bh * NCH + ch) * 4096;
  if (t < 64) {
    size_t ro = ((size_t)b * L_SEQ + l0 + t) * NHM + head;
    float s = dta[ro];
#pragma unroll
    for (int o = 1; o < 64; o <<= 1) {
      float u = __shfl_up(s, o, 64);
      if (t >= o) s += u;
    }
    lcs[t] = s;
    dts[t] = dtp[ro];
  }
#pragma unroll
  for (int it = 0; it < 16; it++) {
    int e = it * 256 + t;
    int j = e >> 6, cc = e & 63;
    const unsigned short* rowp = xcb + (size_t)j * CONVD;
    Xt[cc * 72 + j] = rowp[head * HDM + cc];
    Bs[j * 72 + cc] = rowp[768 + cc];
    Cs[j * 72 + cc] = rowp[832 + cc];
    Hs[j * 72 + cc] = f2bf(Hg[e]);          // Hg layout is [p][n]
  }
  __syncthreads();
  int lane = t & 63, w = t >> 6;
  int wr = (w >> 1) * 32, wc = (w & 1) * 32;
  int fl = lane & 15, kq = lane >> 4;
  int rbase = kq * 4, cl = fl;
  // ---- product 1: S_raw = C @ B^T (contract over n) ----
  f32x4 sacc[2][2];
#pragma unroll
  for (int i = 0; i < 2; i++)
#pragma unroll
    for (int j = 0; j < 2; j++) sacc[i][j] = (f32x4)0.f;
#pragma unroll
  for (int kk = 0; kk < 2; kk++) {
    short8 af[2], bfr[2];
#pragma unroll
    for (int mi = 0; mi < 2; mi++)
      af[mi] = *(const short8*)&Cs[(wr + mi * 16 + fl) * 72 + kk * 32 + kq * 8];
#pragma unroll
    for (int ni = 0; ni < 2; ni++)
      bfr[ni] = *(const short8*)&Bs[(wc + ni * 16 + fl) * 72 + kk * 32 + kq * 8];
#pragma unroll
    for (int mi = 0; mi < 2; mi++)
#pragma unroll
      for (int ni = 0; ni < 2; ni++)
        sacc[mi][ni] = __builtin_amdgcn_mfma_f32_16x16x32_bf16(af[mi], bfr[ni], sacc[mi][ni], 0, 0, 0);
  }
  __syncthreads();   // everyone done reading Cs/Bs fragments
  // ---- build S (mask j<=i, scale by dt[j]*exp(lc[i]-lc[j])); rescale C in place by exp(lc[i]) ----
#pragma unroll
  for (int mi = 0; mi < 2; mi++)
#pragma unroll
    for (int ni = 0; ni < 2; ni++)
#pragma unroll
      for (int r = 0; r < 4; r++) {
        int i = wr + mi * 16 + rbase + r;
        int j = wc + ni * 16 + cl;
        float v = (j <= i) ? sacc[mi][ni][r] * dts[j] * __expf(lcs[i] - lcs[j]) : 0.f;
        Ss[i * 72 + j] = f2bf(v);
      }
#pragma unroll
  for (int it = 0; it < 16; it++) {
    int e = it * 256 + t;
    int i = e >> 6, n = e & 63;
    float cv = bf2f(Cs[i * 72 + n]) * __expf(lcs[i]);
    Cs[i * 72 + n] = f2bf(cv);
  }
  __syncthreads();
  // ---- products 2+3 accumulated: Y = S @ X  +  C'' @ Hprev^T(layout) ----
  f32x4 yacc[2][2];
#pragma unroll
  for (int i = 0; i < 2; i++)
#pragma unroll
    for (int j = 0; j < 2; j++) yacc[i][j] = (f32x4)0.f;
#pragma unroll
  for (int kk = 0; kk < 2; kk++) {
    short8 af[2], bfr[2];
#pragma unroll
    for (int mi = 0; mi < 2; mi++)
      af[mi] = *(const short8*)&Ss[(wr + mi * 16 + fl) * 72 + kk * 32 + kq * 8];
#pragma unroll
    for (int ni = 0; ni < 2; ni++)
      bfr[ni] = *(const short8*)&Xt[(wc + ni * 16 + fl) * 72 + kk * 32 + kq * 8];
#pragma unroll
    for (int mi = 0; mi < 2; mi++)
#pragma unroll
      for (int ni = 0; ni < 2; ni++)
        yacc[mi][ni] = __builtin_amdgcn_mfma_f32_16x16x32_bf16(af[mi], bfr[ni], yacc[mi][ni], 0, 0, 0);
  }
#pragma unroll
  for (int kk = 0; kk < 2; kk++) {
    short8 af[2], bfr[2];
#pragma unroll
    for (int mi = 0; mi < 2; mi++)
      af[mi] = *(const short8*)&Cs[(wr + mi * 16 + fl) * 72 + kk * 32 + kq * 8];
#pragma unroll
    for (int ni = 0; ni < 2; ni++)
      bfr[ni] = *(const short8*)&Hs[(wc + ni * 16 + fl) * 72 + kk * 32 + kq * 8];
#pragma unroll
    for (int mi = 0; mi < 2; mi++)
#pragma unroll
      for (int ni = 0; ni < 2; ni++)
        yacc[mi][ni] = __builtin_amdgcn_mfma_f32_16x16x32_bf16(af[mi], bfr[ni], yacc[mi][ni], 0, 0, 0);
  }
  // ---- epilogue: + D * x, write bf16 ----
  float Dh = Dp[head];
  unsigned short* yb = Ybf + ((size_t)b * L_SEQ + l0) * DIN + head * HDM;
#pragma unroll
  for (int mi = 0; mi < 2; mi++)
#pragma unroll
    for (int ni = 0; ni < 2; ni++)
#pragma unroll
      for (int r = 0; r < 4; r++) {
        int i = wr + mi * 16 + rbase + r;
        int p = wc + ni * 16 + cl;
        float xval = bf2f(Xt[p * 72 + i]);
        yb[(size_t)i * DIN + p] = f2bf(yacc[mi][ni][r] + Dh * xval);
      }
}

// ---------------- gated RMS norm (bf16 y, bf16 z) ----------------
__global__ __launch_bounds__(256) void gate_rms_kernel(unsigned short* __restrict__ Y,
    const unsigned short* __restrict__ Z, const float* __restrict__ mw) {
  int wave = threadIdx.x >> 6, lane = threadIdx.x & 63;
  int row = blockIdx.x * 4 + wave;
  if (row >= NROWS) return;
  unsigned short* y = Y + (size_t)row * DIN;
  const unsigned short* z = Z + (size_t)row * DIN;
  float g[12];
  float ss = 0.f;
#pragma unroll
  for (int q = 0; q < 3; q++) {
    int c = q * 256 + lane * 4;
    uint2 yu = *(const uint2*)&y[c];
    uint2 zu = *(const uint2*)&z[c];
    float y0 = bf2f((unsigned short)(yu.x & 0xffff));
    float y1 = bf2f((unsigned short)(yu.x >> 16));
    float y2 = bf2f((unsigned short)(yu.y & 0xffff));
    float y3 = bf2f((unsigned short)(yu.y >> 16));
    float z0 = bf2f((unsigned short)(zu.x & 0xffff));
    float z1 = bf2f((unsigned short)(zu.x >> 16));
    float z2 = bf2f((unsigned short)(zu.y & 0xffff));
    float z3 = bf2f((unsigned short)(zu.y >> 16));
    float g0 = y0 * siluf(z0), g1 = y1 * siluf(z1);
    float g2 = y2 * siluf(z2), g3 = y3 * siluf(z3);
    ss += g0 * g0 + g1 * g1 + g2 * g2 + g3 * g3;
    g[q * 4 + 0] = g0; g[q * 4 + 1] = g1; g[q * 4 + 2] = g2; g[q * 4 + 3] = g3;
  }
#pragma unroll
  for (int o = 32; o > 0; o >>= 1) ss += __shfl_xor(ss, o, 64);
  float rs = rsqrtf(ss * (1.f / 768.f) + 1e-5f);
#pragma unroll
  for (int q = 0; q < 3; q++) {
    int c = q * 256 + lane * 4;
    float4 m = *(const float4*)&mw[c];
    uint2 pk;
    pk.x = pk_bf16(g[q*4+0] * rs * m.x, g[q*4+1] * rs * m.y);
    pk.y = pk_bf16(g[q*4+2] * rs * m.z, g[q*4+3] * rs * m.w);
    *(uint2*)&y[c] = pk;
  }
}

// ---------------- attention gate ----------------
__global__ __launch_bounds__(256) void attgate_kernel(const unsigned short* __restrict__ XN,
    const float* __restrict__ gw, const float* __restrict__ gb, float* __restrict__ G) {
  int wave = threadIdx.x >> 6, lane = threadIdx.x & 63;
  int row = blockIdx.x * 4 + wave;
  if (row >= NROWS) return;
  const unsigned short* x = XN + (size_t)row * CDIM;
  float acc[12] = {};
#pragma unroll
  for (int q = 0; q < 6; q++) {
    int k = q * 64 + lane;
    float xv = bf2f(x[k]);
    const float* wr = gw + (size_t)k * 12;
    float4 w0 = *(const float4*)&wr[0];
    float4 w1 = *(const float4*)&wr[4];
    float4 w2 = *(const float4*)&wr[8];
    acc[0] += xv * w0.x; acc[1] += xv * w0.y; acc[2]  += xv * w0.z; acc[3]  += xv * w0.w;
    acc[4] += xv * w1.x; acc[5] += xv * w1.y; acc[6]  += xv * w1.z; acc[7]  += xv * w1.w;
    acc[8] += xv * w2.x; acc[9] += xv * w2.y; acc[10] += xv * w2.z; acc[11] += xv * w2.w;
  }
#pragma unroll
  for (int h = 0; h < 12; h++)
#pragma unroll
    for (int o = 32; o > 0; o >>= 1) acc[h] += __shfl_xor(acc[h], o, 64);
  if (lane == 0) {
#pragma unroll
    for (int h = 0; h < 12; h++) {
      float v = acc[h] + gb[h];
      G[(size_t)row * 12 + h] = 1.f / (1.f + expf(-v));
    }
  }
}

// ---------------- windowed attention via MFMA: one wave per (window, head) ----------------
__global__ __launch_bounds__(64) void attn_kernel(const unsigned short* __restrict__ QKV,
    const float* __restrict__ G, unsigned short* __restrict__ XA) {
  __shared__ unsigned short Pl[64 * 72];   // P [i][j], row stride 72 (144B)
  __shared__ unsigned short Vt[32 * 72];   // V^T [d][j], slot-swizzled: slot' = (j>>3) ^ (d>>3)
  int blk = blockIdx.x;
  int head = blk % NHA;
  int win = blk / NHA;
  int b = win >> 6;
  int wrw = win & 63;
  int wy = wrw >> 3, wx = wrw & 7;
  int lane = threadIdx.x;
  int fl = lane & 15, kq = lane >> 4;
  const float scale = 0.17677669529663688f;
  size_t bbase = (size_t)b * L_SEQ;
  const unsigned short* qb = QKV + head * 32;

  short8 aq[4], bk[4];
#pragma unroll
  for (int ti = 0; ti < 4; ti++) {
    int tok = ti * 16 + fl; if (tok > 48) tok = 48;
    int iy = tok / 7, ix = tok - iy * 7;
    size_t r = bbase + (size_t)(wy * 7 + iy) * 56 + wx * 7 + ix;
    aq[ti] = *(const short8*)&qb[r * 1152 + kq * 8];
    bk[ti] = *(const short8*)&qb[r * 1152 + 384 + kq * 8];
  }
#pragma unroll
  for (int it = 0; it < 4; it++) {
    int j = (lane >> 2) + it * 16;
    int dc = (lane & 3) * 8;
    ushort8 v8 = (ushort8)0;
    if (j <= 48) {
      int iy = j / 7, ix = j - iy * 7;
      size_t r = bbase + (size_t)(wy * 7 + iy) * 56 + wx * 7 + ix;
      v8 = *(const ushort8*)&qb[r * 1152 + 768 + dc];
    }
#pragma unroll
    for (int q2 = 0; q2 < 8; q2++) {
      int d = dc + q2;
      Vt[d * 72 + (((j >> 3) ^ (d >> 3)) << 3) + (j & 7)] = v8[q2];
    }
  }
  f32x4 sacc[4][4];
#pragma unroll
  for (int tj = 0; tj < 4; tj++)
#pragma unroll
    for (int ti = 0; ti < 4; ti++)
      sacc[tj][ti] = __builtin_amdgcn_mfma_f32_16x16x32_bf16(bk[tj], aq[ti], (f32x4)0.f, 0, 0, 0);
#pragma unroll
  for (int ti = 0; ti < 4; ti++) {
    float mx = -1e30f;
#pragma unroll
    for (int tj = 0; tj < 4; tj++)
#pragma unroll
      for (int r = 0; r < 4; r++) {
        int j = tj * 16 + kq * 4 + r;
        float v = (j < 49) ? sacc[tj][ti][r] * scale : -1e30f;
        sacc[tj][ti][r] = v;
        mx = fmaxf(mx, v);
      }
    mx = fmaxf(mx, __shfl_xor(mx, 16, 64));
    mx = fmaxf(mx, __shfl_xor(mx, 32, 64));
    float sum = 0.f;
#pragma unroll
    for (int tj = 0; tj < 4; tj++)
#pragma unroll
      for (int r = 0; r < 4; r++) {
        float e = __expf(sacc[tj][ti][r] - mx);
        sacc[tj][ti][r] = e;
        sum += e;
      }
    sum += __shfl_xor(sum, 16, 64);
    sum += __shfl_xor(sum, 32, 64);
    float inv = 1.f / sum;
    int i = ti * 16 + fl;
#pragma unroll
    for (int tj = 0; tj < 4; tj++)
#pragma unroll
      for (int r = 0; r < 4; r++) {
        int j = tj * 16 + kq * 4 + r;
        Pl[i * 72 + j] = f2bf(sacc[tj][ti][r] * inv);
      }
  }
  f32x4 oacc[4][2];
#pragma unroll
  for (int i2 = 0; i2 < 4; i2++)
#pragma unroll
    for (int nd = 0; nd < 2; nd++) oacc[i2][nd] = (f32x4)0.f;
#pragma unroll
  for (int kk = 0; kk < 2; kk++) {
    short8 ap[4], bv[2];
#pragma unroll
    for (int i2 = 0; i2 < 4; i2++)
      ap[i2] = *(const short8*)&Pl[(i2 * 16 + fl) * 72 + kk * 32 + kq * 8];
#pragma unroll
    for (int nd = 0; nd < 2; nd++) {
      int d = nd * 16 + fl;
      bv[nd] = *(const short8*)&Vt[d * 72 + (((kk * 4 + kq) ^ (d >> 3)) << 3)];
    }
#pragma unroll
    for (int i2 = 0; i2 < 4; i2++)
#pragma unroll
      for (int nd = 0; nd < 2; nd++)
        oacc[i2][nd] = __builtin_amdgcn_mfma_f32_16x16x32_bf16(ap[i2], bv[nd], oacc[i2][nd], 0, 0, 0);
  }
#pragma unroll
  for (int i2 = 0; i2 < 4; i2++) {
#pragma unroll
    for (int r = 0; r < 4; r++) {
      int i = i2 * 16 + kq * 4 + r;
      if (i > 48) continue;
      int iy = i / 7, ix = i - iy * 7;
      size_t rg = bbase + (size_t)(wy * 7 + iy) * 56 + wx * 7 + ix;
      float g = G[rg * 12 + head];
#pragma unroll
      for (int nd = 0; nd < 2; nd++)
        XA[rg * CDIM + head * 32 + nd * 16 + fl] = f2bf(oacc[i2][nd][r] * g);
    }
  }
}

// ---------------- host launch ----------------
extern "C" void kernel_launch(void* const* d_in, const int* in_sizes, int n_in,
                              void* d_out, int out_size, void* d_ws, size_t ws_size,
                              hipStream_t stream) {
  const float* x        = (const float*)d_in[0];
  const float* norm1_w  = (const float*)d_in[1];
  const float* norm1_b  = (const float*)d_in[2];
  const float* W_in     = (const float*)d_in[3];
  const float* conv_w   = (const float*)d_in[4];
  const float* conv_b   = (const float*)d_in[5];
  const float* dt_bias  = (const float*)d_in[6];
  const float* A_log    = (const float*)d_in[7];
  const float* Dp       = (const float*)d_in[8];
  const float* mnorm_w  = (const float*)d_in[9];
  const float* W_out    = (const float*)d_in[10];
  const float* qkv_w    = (const float*)d_in[11];
  const float* qkv_b    = (const float*)d_in[12];
  const float* gate_w   = (const float*)d_in[13];
  const float* gate_b   = (const float*)d_in[14];
  const float* proj_w   = (const float*)d_in[15];
  const float* proj_b   = (const float*)d_in[16];
  const float* fusion_w = (const float*)d_in[17];
  const float* fusion_b = (const float*)d_in[18];
  const float* norm2_w  = (const float*)d_in[19];
  const float* norm2_b  = (const float*)d_in[20];
  const float* fc1_w    = (const float*)d_in[21];
  const float* fc1_b    = (const float*)d_in[22];
  const float* fc2_w    = (const float*)d_in[23];
  const float* fc2_b    = (const float*)d_in[24];
  float* OUT = (float*)d_out;

  float* ws = (float*)d_ws;
  unsigned short* XNBF = (unsigned short*)ws;              // 25088x384 bf16
  float* XC_  = ws + 4816896;                              // XC bf16; later CATBF+XABF
  float* SCR  = XC_ + 22478848;                            // ZX bf16 -> H fp32 -> z bf16 -> QKVbf -> M1bf
  unsigned short* YBF = (unsigned short*)(SCR + 22478848); // 25088x768 bf16
  unsigned short* WT  = (unsigned short*)(SCR + 22478848 + 9633792); // 3,047,424 bf16
  float* DT_ = (float*)(WT + 3047424);                     // 301,056
  float* DA_ = DT_ + 301056;                               // 301,056 (log-decay)
  float* G_  = DA_ + 301056;                               // 301,056
  float* QS_ = G_  + 301056;                               // 5,376 (need 4,704)

  unsigned short* ZXBF  = (unsigned short*)SCR;            // combined xBC+dt bf16 [25088][1024]
  unsigned short* XCBF  = (unsigned short*)XC_;            // conv output bf16 [25088][896]
  float* H_ = SCR;                                         // 96*49*4096 = 19,267,584 fl
  unsigned short* ZBF   = (unsigned short*)SCR;            // z bf16 (after H consumed)
  unsigned short* QKVBF = (unsigned short*)SCR;
  unsigned short* M1BF  = (unsigned short*)SCR;
  unsigned short* CATBF = (unsigned short*)XC_;
  unsigned short* XABF  = (unsigned short*)(XC_ + 9633792);

  unsigned short* wt_xbcdt = WT;           // 1024x384 (cols 768..1675 of W_in, padded)
  unsigned short* wt_z    = WT + 393216;   // 768x384
  unsigned short* wt_out  = WT + 688128;   // 384x768
  unsigned short* wt_qkv  = WT + 983040;   // 1152x384
  unsigned short* wt_proj = WT + 1425408;  // 384x384
  unsigned short* wt_fus  = WT + 1572864;  // 384x768
  unsigned short* wt_fc1  = WT + 1867776;  // 1536x384
  unsigned short* wt_fc2  = WT + 2457600;  // 384x1536

  wconv_kernel<<<dim3(12,  29), 256, 0, stream>>>(W_in + 768,  wt_xbcdt, 384, 908, DPROJ);
  wconv_kernel<<<dim3(12,  24), 256, 0, stream>>>(W_in,        wt_z,    384,  768, DPROJ);
  wconv_kernel<<<dim3(24,  12), 256, 0, stream>>>(W_out,       wt_out,  768,  384, 384);
  wconv_kernel<<<dim3(12,  36), 256, 0, stream>>>(qkv_w,       wt_qkv,  384, 1152, 1152);
  wconv_kernel<<<dim3(12,  12), 256, 0, stream>>>(proj_w,      wt_proj, 384,  384, 384);
  wconv_kernel<<<dim3(24,  12), 256, 0, stream>>>(fusion_w,    wt_fus,  768,  384, 384);
  wconv_kernel<<<dim3(12,  48), 256, 0, stream>>>(fc1_w,       wt_fc1,  384, 1536, 1536);
  wconv_kernel<<<dim3(48,  12), 256, 0, stream>>>(fc2_w,       wt_fc2, 1536,  384, 384);

  ln_kernel<<<6272, 256, 0, stream>>>(x, norm1_w, norm1_b, XNBF);

  // combined xBC+dt projection: [25088][908] -> ZXBF (ldc=1024)
  gemm_bf<0, false, false, true><<<dim3(8, 196), 256, 0, stream>>>(
      XNBF, wt_xbcdt, ZXBF, nullptr, nullptr, 0, NROWS, 908, CDIM, CDIM, ZXLD, 0);
  conv_bf_kernel<<<392, 256, 0, stream>>>(ZXBF, conv_w, conv_b, XCBF, ZXLD);
  dtprep_kernel<<<(NROWS * NHM + 255) / 256, 256, 0, stream>>>(ZXBF, dt_bias, A_log, DT_, DA_);

  mscan1_kernel<<<dim3(NCH, 96), 256, 0, stream>>>(XCBF, DT_, DA_, H_, QS_);
  scomb_kernel<<<dim3(96, 16), 64, 0, stream>>>(H_, QS_);
  mscan2_kernel<<<dim3(NCH, 96), 256, 0, stream>>>(XCBF, DT_, DA_, H_, Dp, YBF);

  gemm_bf<0, false, false, true><<<dim3(6, 196), 256, 0, stream>>>(
      XNBF, wt_z, ZBF, nullptr, nullptr, 0, NROWS, DIN, CDIM, CDIM, DIN, 0);
  gate_rms_kernel<<<6272, 256, 0, stream>>>(YBF, ZBF, mnorm_w);

  gemm_bf<0, false, false, true><<<dim3(3, 196), 256, 0, stream>>>(
      YBF, wt_out, CATBF, nullptr, nullptr, 0, NROWS, CDIM, DIN, DIN, 2 * CDIM, 0);

  attgate_kernel<<<6272, 256, 0, stream>>>(XNBF, gate_w, gate_b, G_);

  gemm_bf<0, true, false, true><<<dim3(9, 196), 256, 0, stream>>>(
      XNBF, wt_qkv, QKVBF, qkv_b, nullptr, 0, NROWS, 3 * CDIM, CDIM, CDIM, 3 * CDIM, 0);
  attn_kernel<<<512 * NHA, 64, 0, stream>>>(QKVBF, G_, XABF);

  gemm_bf<0, true, false, true><<<dim3(3, 196), 256, 0, stream>>>(
      XABF, wt_proj, CATBF, proj_b, nullptr, 0, NROWS, CDIM, CDIM, CDIM, 2 * CDIM, CDIM);

  gemm_bf<0, true, true, false><<<dim3(3, 196), 256, 0, stream>>>(
      CATBF, wt_fus, OUT, fusion_b, x, CDIM, NROWS, CDIM, 2 * CDIM, 2 * CDIM, CDIM, 0);

  ln_kernel<<<6272, 256, 0, stream>>>(OUT, norm2_w, norm2_b, XNBF);

  gemm_bf<1, true, false, true><<<dim3(12, 196), 256, 0, stream>>>(
      XNBF, wt_fc1, M1BF, fc1_b, nullptr, 0, NROWS, 4 * CDIM, CDIM, CDIM, 4 * CDIM, 0);
  gemm_bf<0, true, true, false><<<dim3(3, 196), 256, 0, stream>>>(
      M1BF, wt_fc2, OUT, fc2_b, OUT, CDIM, NROWS, CDIM, 4 * CDIM, 4 * CDIM, CDIM, 0);
}

// Round 8
// 656.250 us; speedup vs baseline: 1.0129x; 1.0129x over previous
//
#include <hip/hip_runtime.h>
#include <math.h>

static constexpr int L_SEQ  = 3136;
static constexpr int NBATCH = 8;
static constexpr int CDIM   = 384;
static constexpr int DIN    = 768;
static constexpr int NHM    = 12;
static constexpr int HDM    = 64;
static constexpr int DPROJ  = 1676;   // 2*768 + 2*64 + 12
static constexpr int CONVD  = 896;    // 768 + 128
static constexpr int NROWS  = NBATCH * L_SEQ; // 25088
static constexpr int NHA    = 12;
static constexpr int NCH    = 49;     // chunks per sequence
static constexpr int CHT    = 64;     // tokens per chunk (49*64 = 3136)
static constexpr int CTK    = 28;     // tokens per conv thread (3136/28 = 112)
static constexpr int ZXLD   = 1024;   // combined xBC+dt output stride (908 padded)

typedef __attribute__((ext_vector_type(8))) short short8;
typedef __attribute__((ext_vector_type(8))) unsigned short ushort8;
typedef __attribute__((ext_vector_type(4))) float f32x4;
typedef const unsigned int __attribute__((address_space(1)))* gua_t;
typedef unsigned int __attribute__((address_space(3)))* lua_t;

__device__ __forceinline__ float siluf(float x) { return x / (1.f + __expf(-x)); }
__device__ __forceinline__ unsigned short f2bf(float f) {
  unsigned int u = __float_as_uint(f);
  u += 0x7fff + ((u >> 16) & 1);
  return (unsigned short)(u >> 16);
}
__device__ __forceinline__ float bf2f(unsigned short h) {
  return __uint_as_float(((unsigned int)h) << 16);
}
// GELU via A&S 7.1.25 3-term erf (|err|<=2.5e-5, far below bf16 ulp):
// gelu(v) = 0.5 v + 0.5|v| * erf(|v|/sqrt2)
__device__ __forceinline__ float geluf(float v) {
  float ax = fabsf(v) * 0.70710678118654752f;
  float t = __builtin_amdgcn_rcpf(fmaf(0.47047f, ax, 1.f));
  float p = t * fmaf(t, fmaf(t, 0.7478556f, -0.0958798f), 0.3480242f);
  float e = __expf(-ax * ax);
  float r = 1.f - p * e;
  float h = 0.5f * v;
  return fmaf(fabsf(h), r, h);
}
__device__ __forceinline__ unsigned int pk_bf16(float lo, float hi) {
  unsigned int d;
  asm("v_cvt_pk_bf16_f32 %0, %1, %2" : "=v"(d) : "v"(lo), "v"(hi));
  return d;
}

// ---------------- LayerNorm: one wave per row, C=384, bf16 out ----------------
__global__ __launch_bounds__(256) void ln_kernel(const float* __restrict__ in,
    const float* __restrict__ w, const float* __restrict__ b, unsigned short* __restrict__ out) {
  int wave = threadIdx.x >> 6, lane = threadIdx.x & 63;
  int row = blockIdx.x * 4 + wave;
  if (row >= NROWS) return;
  const float* r = in + (size_t)row * CDIM;
  float2 v[3];
  float s1 = 0.f, s2 = 0.f;
#pragma unroll
  for (int q = 0; q < 3; q++) {
    v[q] = *(const float2*)&r[q * 128 + lane * 2];
    s1 += v[q].x + v[q].y;
    s2 += v[q].x * v[q].x + v[q].y * v[q].y;
  }
#pragma unroll
  for (int o = 32; o > 0; o >>= 1) { s1 += __shfl_xor(s1, o, 64); s2 += __shfl_xor(s2, o, 64); }
  float mu = s1 * (1.f / 384.f);
  float var = s2 * (1.f / 384.f) - mu * mu;
  float rs = rsqrtf(var + 1e-5f);
  unsigned short* o = out + (size_t)row * CDIM;
#pragma unroll
  for (int q = 0; q < 3; q++) {
    int c = q * 128 + lane * 2;
    float2 wv = *(const float2*)&w[c];
    float2 bv = *(const float2*)&b[c];
    float ox = (v[q].x - mu) * rs * wv.x + bv.x;
    float oy = (v[q].y - mu) * rs * wv.y + bv.y;
    *(unsigned int*)&o[c] = pk_bf16(ox, oy);
  }
}

// ---------------- weight convert + transpose: W[K][N] fp32 -> WT[Np][K] bf16 ----------------
__global__ __launch_bounds__(256) void wconv_kernel(const float* __restrict__ W,
    unsigned short* __restrict__ WT, int K, int N, int ldw) {
  __shared__ float tile[32][33];
  int k0 = blockIdx.x * 32, n0 = blockIdx.y * 32;
  int tx = threadIdx.x & 31, ty = threadIdx.x >> 5;
#pragma unroll
  for (int j = 0; j < 4; j++) {
    int k = k0 + ty + j * 8;
    int n = n0 + tx;
    tile[ty + j * 8][tx] = (n < N) ? W[(size_t)k * ldw + n] : 0.f;
  }
  __syncthreads();
#pragma unroll
  for (int j = 0; j < 4; j++) {
    int n = n0 + ty + j * 8;
    int k = k0 + tx;
    WT[(size_t)n * K + k] = f2bf(tile[tx][ty + j * 8]);
  }
}

// ---------------- bf16 MFMA GEMM: 3-buffer depth-2 counted-vmcnt pipeline,
// ---------------- slot-XOR LDS swizzle, XCD swizzle, transposed acc + swizzled LDS-bounce epilogue
template<int ACT, bool HASBIAS, bool HASRES, bool OUTBF>
__global__ __launch_bounds__(256, 4) void gemm_bf(
    const unsigned short* __restrict__ A, const unsigned short* __restrict__ WT,
    void* __restrict__ Cp, const float* __restrict__ bias,
    const float* __restrict__ res, int ldr,
    int M, int N, int K, int lda, int ldc, int coff)
{
  __shared__ unsigned short SMEM[24576];   // A bufs @ {0,4096,8192}, W bufs @ {12288,+4096,+8192}; reused as 128x128 bounce
  int t = threadIdx.x;
  // XCD-aware bijective remap (m204)
  int gx = gridDim.x;
  int nwg = gx * gridDim.y;
  int orig = blockIdx.y * gx + blockIdx.x;
  int qq = nwg >> 3, rr = nwg & 7;
  int xcd = orig & 7, seq = orig >> 3;
  int wgid = (xcd < rr ? xcd * (qq + 1) : rr * (qq + 1) + (xcd - rr) * qq) + seq;
  int m0 = (wgid / gx) * 128, n0 = (wgid % gx) * 128;

  int lane = t & 63, w = t >> 6;
  int wr = (w >> 1) * 64, wc = (w & 1) * 64;
  int fl = lane & 15, kq = lane >> 4;
  int so = (kq ^ ((lane >> 1) & 3)) * 8;   // swizzled 16B slot for ds_read

  // staging: thread t owns chunk t (rows 0..63) and chunk 256+t (rows 64..127); advance 32 elems/tile
  int srow = t >> 2, sq = t & 3;
  int q0 = sq ^ ((srow >> 1) & 3);
  const unsigned short* pA0 = A  + (size_t)(m0 + srow) * lda + q0 * 8;
  const unsigned short* pA1 = A  + (size_t)(m0 + 64 + srow) * lda + q0 * 8;
  const unsigned short* pW0 = WT + (size_t)(n0 + srow) * K + q0 * 8;
  const unsigned short* pW1 = WT + (size_t)(n0 + 64 + srow) * K + q0 * 8;

  f32x4 acc[4][4];     // transposed: acc[mi][ni] regs = n (kq*4+r), lanes = m (fl)
#pragma unroll
  for (int i = 0; i < 4; i++)
#pragma unroll
    for (int j = 0; j < 4; j++) acc[i][j] = (f32x4)0.f;

  auto STAGE = [&](int buf) {
    unsigned short* as = SMEM + buf * 4096;
    unsigned short* ws = SMEM + 12288 + buf * 4096;
    __builtin_amdgcn_global_load_lds((gua_t)pA0, (lua_t)as + t * 4, 16, 0, 0);
    __builtin_amdgcn_global_load_lds((gua_t)pA1, (lua_t)(as + 2048) + t * 4, 16, 0, 0);
    __builtin_amdgcn_global_load_lds((gua_t)pW0, (lua_t)ws + t * 4, 16, 0, 0);
    __builtin_amdgcn_global_load_lds((gua_t)pW1, (lua_t)(ws + 2048) + t * 4, 16, 0, 0);
    pA0 += 32; pA1 += 32; pW0 += 32; pW1 += 32;
  };

  int nk = K >> 5;               // all K here are >= 64, so nk >= 2
  STAGE(0);
  STAGE(1);
  int cb = 0, sb = 2;
  for (int ks = 0; ks < nk; ks++) {
    if (ks + 1 < nk) {
      asm volatile("s_waitcnt vmcnt(4)" ::: "memory");   // tile ks landed; tile ks+1 stays in flight
    } else {
      asm volatile("s_waitcnt vmcnt(0)" ::: "memory");
    }
    __builtin_amdgcn_s_barrier();
    asm volatile("" ::: "memory");
    __builtin_amdgcn_sched_barrier(0);
    if (ks + 2 < nk) {           // buffer sb's readers (tile ks-1) drained at the barrier above
      STAGE(sb);
      sb = sb == 2 ? 0 : sb + 1;
    }
    const unsigned short* as = SMEM + cb * 4096;
    const unsigned short* ws = SMEM + 12288 + cb * 4096;
    cb = cb == 2 ? 0 : cb + 1;
    short8 af[4], bfr[4];
#pragma unroll
    for (int mi = 0; mi < 4; mi++) af[mi] = *(const short8*)&as[(wr + mi * 16 + fl) * 32 + so];
#pragma unroll
    for (int ni = 0; ni < 4; ni++) bfr[ni] = *(const short8*)&ws[(wc + ni * 16 + fl) * 32 + so];
    // swapped operands: output rows = n (from W frag), cols = m (from A frag)
#pragma unroll
    for (int mi = 0; mi < 4; mi++)
#pragma unroll
      for (int ni = 0; ni < 4; ni++)
        acc[mi][ni] = __builtin_amdgcn_mfma_f32_16x16x32_bf16(bfr[ni], af[mi], acc[mi][ni], 0, 0, 0);
  }
  // epilogue: lane holds m = wr+mi*16+fl, n = wc+ni*16+kq*4+{0..3}
  if (OUTBF) {
    __syncthreads();   // all waves done reading pipeline buffers; reuse SMEM as 128x128 bounce tile
    float4 bv[4];
    if (HASBIAS) {
#pragma unroll
      for (int ni = 0; ni < 4; ni++) bv[ni] = *(const float4*)&bias[n0 + wc + ni * 16 + kq * 4];
    }
#pragma unroll
    for (int mi = 0; mi < 4; mi++) {
      int mloc = wr + mi * 16 + fl;
#pragma unroll
      for (int ni = 0; ni < 4; ni++) {
        float v0 = acc[mi][ni][0], v1 = acc[mi][ni][1];
        float v2 = acc[mi][ni][2], v3 = acc[mi][ni][3];
        if (HASBIAS) { v0 += bv[ni].x; v1 += bv[ni].y; v2 += bv[ni].z; v3 += bv[ni].w; }
        if (ACT == 1) { v0 = geluf(v0); v1 = geluf(v1); v2 = geluf(v2); v3 = geluf(v3); }
        int gidx = (wc >> 2) + ni * 4 + kq;          // 8B granule index in row (0..31)
        int gs = gidx ^ (mloc & 15);                 // bank-spread swizzle
        uint2 pk; pk.x = pk_bf16(v0, v1); pk.y = pk_bf16(v2, v3);
        *(uint2*)&SMEM[mloc * 128 + gs * 4] = pk;
      }
    }
    __syncthreads();
    unsigned short* outp = (unsigned short*)Cp + coff + n0;
#pragma unroll
    for (int it2 = 0; it2 < 16; it2++) {
      int gg = it2 * 256 + t;
      int row = gg >> 5, g = gg & 31;
      uint2 v = *(const uint2*)&SMEM[row * 128 + (g ^ (row & 15)) * 4];
      *(uint2*)&outp[(size_t)(m0 + row) * ldc + g * 4] = v;
    }
  } else {
    int rbase = kq * 4;
    float* outp = (float*)Cp + coff;
#pragma unroll
    for (int mi = 0; mi < 4; mi++) {
      int m = m0 + wr + mi * 16 + fl;
      float* rowp = outp + (size_t)m * ldc + n0;
#pragma unroll
      for (int ni = 0; ni < 4; ni++) {
        int nb = wc + ni * 16 + rbase;
        float4 v;
        v.x = acc[mi][ni][0]; v.y = acc[mi][ni][1];
        v.z = acc[mi][ni][2]; v.w = acc[mi][ni][3];
        if (HASBIAS) {
          float4 bvv = *(const float4*)&bias[n0 + nb];
          v.x += bvv.x; v.y += bvv.y; v.z += bvv.z; v.w += bvv.w;
        }
        if (ACT == 1) { v.x = geluf(v.x); v.y = geluf(v.y); v.z = geluf(v.z); v.w = geluf(v.w); }
        if (HASRES) {
          float4 rv = *(const float4*)&res[(size_t)m * ldr + n0 + nb];
          v.x += rv.x; v.y += rv.y; v.z += rv.z; v.w += rv.w;
        }
        *(float4*)&rowp[nb] = v;
      }
    }
  }
}

// ---------------- dt prep: read bf16 dt slice of combined ZX; DA holds LOG-decay ----------------
__global__ void dtprep_kernel(const unsigned short* __restrict__ ZX, const float* __restrict__ dt_bias,
    const float* __restrict__ A_log, float* __restrict__ DT, float* __restrict__ DA) {
  int idx = blockIdx.x * blockDim.x + threadIdx.x;
  if (idx >= NROWS * NHM) return;
  int h = idx % NHM;
  int row = idx / NHM;
  float v = bf2f(ZX[(size_t)row * ZXLD + 896 + h]) + dt_bias[h];
  float sp = (v > 20.f) ? v : log1pf(expf(v));
  DT[idx] = sp;
  DA[idx] = -expf(A_log[h]) * sp;   // log of decay (<= 0)
}

// ---------------- depthwise causal conv (k=4) + bias + silu; bf16 in/out, reg shift history ----------------
__global__ __launch_bounds__(256) void conv_bf_kernel(const unsigned short* __restrict__ xbc,
    const float* __restrict__ cw, const float* __restrict__ cb, unsigned short* __restrict__ XC,
    int ldin) {
  int t = blockIdx.x * 256 + threadIdx.x;
  int c8 = t % 112;                 // 8-channel group within row (112*8 = 896)
  int rg = t / 112;                 // b * 112 + lchunk
  int b = rg / 112, lc = rg % 112;
  int l0 = lc * CTK;
  int c0 = c8 * 8;
  float w0[8], w1[8], w2[8], w3[8], bq[8];
#pragma unroll
  for (int i = 0; i < 8; i++) {
    bq[i] = cb[c0 + i];
    float4 w4 = *(const float4*)&cw[(c0 + i) * 4];
    w0[i] = w4.x; w1[i] = w4.y; w2[i] = w4.z; w3[i] = w4.w;
  }
  const unsigned short* base = xbc + (size_t)b * L_SEQ * ldin + c0;
  unsigned short* obase = XC + (size_t)b * L_SEQ * CONVD + c0;
  ushort8 h0 = (ushort8)0, h1 = (ushort8)0, h2 = (ushort8)0;
  if (l0 >= 3) {
    h0 = *(const ushort8*)&base[(size_t)(l0 - 3) * ldin];
    h1 = *(const ushort8*)&base[(size_t)(l0 - 2) * ldin];
    h2 = *(const ushort8*)&base[(size_t)(l0 - 1) * ldin];
  }
  for (int i = 0; i < CTK; i++) {
    ushort8 cur = *(const ushort8*)&base[(size_t)(l0 + i) * ldin];
    ushort8 ov;
#pragma unroll
    for (int q = 0; q < 8; q++) {
      float acc = bq[q] + w0[q] * bf2f(h0[q]) + w1[q] * bf2f(h1[q])
                + w2[q] * bf2f(h2[q]) + w3[q] * bf2f(cur[q]);
      ov[q] = f2bf(siluf(acc));
    }
    *(ushort8*)&obase[(size_t)(l0 + i) * CONVD] = ov;
    h0 = h1; h1 = h2; h2 = cur;
  }
}

// ---------------- chunked SSD scan pass 1 (MFMA): G^T[p][n] = sum_j X[j][p] * (B[j][n]*w[j]) ----------------
__global__ __launch_bounds__(256) void mscan1_kernel(const unsigned short* __restrict__ XC,
    const float* __restrict__ dtp, const float* __restrict__ dta,
    float* __restrict__ H, float* __restrict__ QS) {
  __shared__ unsigned short Xt[64 * 72];   // X^T [p][j]
  __shared__ unsigned short Bt[64 * 72];   // (B*w)^T [n][j]
  __shared__ float lcs[64];
  __shared__ float wss[64];
  int ch = blockIdx.x, bh = blockIdx.y;
  int b = bh / NHM, head = bh - b * NHM;
  int t = threadIdx.x;
  int l0 = ch * CHT;
  const unsigned short* xcb = XC + ((size_t)b * L_SEQ + l0) * CONVD;
  if (t < 64) {
    size_t ro = ((size_t)b * L_SEQ + l0 + t) * NHM + head;
    float s = dta[ro];
#pragma unroll
    for (int o = 1; o < 64; o <<= 1) {
      float u = __shfl_up(s, o, 64);
      if (t >= o) s += u;
    }
    float lc63 = __shfl(s, 63, 64);
    lcs[t] = s;
    wss[t] = dtp[ro] * __expf(lc63 - s);
    if (t == 63) QS[bh * NCH + ch] = __expf(s);
  }
  __syncthreads();
#pragma unroll
  for (int it = 0; it < 16; it++) {
    int e = it * 256 + t;
    int j = e >> 6, cc = e & 63;
    const unsigned short* rowp = xcb + (size_t)j * CONVD;
    Xt[cc * 72 + j] = rowp[head * HDM + cc];
    Bt[cc * 72 + j] = f2bf(bf2f(rowp[768 + cc]) * wss[j]);
  }
  __syncthreads();
  int lane = t & 63, w = t >> 6;
  int wr = (w >> 1) * 32, wc = (w & 1) * 32;
  int fl = lane & 15, kq = lane >> 4;
  f32x4 acc[2][2];
#pragma unroll
  for (int i = 0; i < 2; i++)
#pragma unroll
    for (int j = 0; j < 2; j++) acc[i][j] = (f32x4)0.f;
#pragma unroll
  for (int kk = 0; kk < 2; kk++) {
    short8 af[2], bfr[2];
#pragma unroll
    for (int mi = 0; mi < 2; mi++)
      af[mi] = *(const short8*)&Xt[(wr + mi * 16 + fl) * 72 + kk * 32 + kq * 8];
#pragma unroll
    for (int ni = 0; ni < 2; ni++)
      bfr[ni] = *(const short8*)&Bt[(wc + ni * 16 + fl) * 72 + kk * 32 + kq * 8];
#pragma unroll
    for (int mi = 0; mi < 2; mi++)
#pragma unroll
      for (int ni = 0; ni < 2; ni++)
        acc[mi][ni] = __builtin_amdgcn_mfma_f32_16x16x32_bf16(af[mi], bfr[ni], acc[mi][ni], 0, 0, 0);
  }
  float* Hp = H + ((size_t)bh * NCH + ch) * 4096;
  int rbase = kq * 4, cl = fl;
#pragma unroll
  for (int mi = 0; mi < 2; mi++)
#pragma unroll
    for (int ni = 0; ni < 2; ni++)
#pragma unroll
      for (int r = 0; r < 4; r++)
        Hp[(size_t)(wr + mi * 16 + rbase + r) * 64 + wc + ni * 16 + cl] = acc[mi][ni][r];
}

// ---------------- scan combine (exclusive prefix over chunks) ----------------
__global__ __launch_bounds__(64) void scomb_kernel(float* __restrict__ H,
    const float* __restrict__ QS) {
  int bh = blockIdx.x;
  int e = (blockIdx.y * 64 + threadIdx.x) * 4;
  float4 cur = make_float4(0.f, 0.f, 0.f, 0.f);
  for (int s = 0; s < NCH; s++) {
    float* Hp = H + ((size_t)bh * NCH + s) * 4096 + e;
    float q = QS[bh * NCH + s];
    float4 tmp = *(float4*)Hp;
    *(float4*)Hp = cur;
    cur.x = q * cur.x + tmp.x;
    cur.y = q * cur.y + tmp.y;
    cur.z = q * cur.z + tmp.z;
    cur.w = q * cur.w + tmp.w;
  }
}

// ---------------- chunked SSD scan pass 2 (MFMA) ----------------
__global__ __launch_bounds__(256) void mscan2_kernel(const unsigned short* __restrict__ XC,
    const float* __restrict__ dtp, const float* __restrict__ dta,
    const float* __restrict__ H, const float* __restrict__ Dp,
    unsigned short* __restrict__ Ybf) {
  __shared__ unsigned short Cs[64 * 72];   // C [i][n] (later scaled by exp(lc[i]))
  __shared__ unsigned short Bs[64 * 72];   // B [j][n]
  __shared__ unsigned short Xt[64 * 72];   // X^T [p][j]
  __shared__ unsigned short Hs[64 * 72];   // Hprev [p][n]
  __shared__ unsigned short Ss[64 * 72];   // S [i][j] masked+scaled
  __shared__ float lcs[64];
  __shared__ float dts[64];
  int ch = blockIdx.x, bh = blockIdx.y;
  int b = bh / NHM, head = bh - b * NHM;
  int t = threadIdx.x;
  int l0 = ch * CHT;
  const unsigned short* xcb = XC + ((size_t)b * L_SEQ + l0) * CONVD;
  const float* Hg = H + ((size_t)bh * NCH + ch) * 4096;
  if (t < 64) {
    size_t ro = ((size_t)b * L_SEQ + l0 + t) * NHM + head;
    float s = dta[ro];
#pragma unroll
    for (int o = 1; o < 64; o <<= 1) {
      float u = __shfl_up(s, o, 64);
      if (t >= o) s += u;
    }
    lcs[t] = s;
    dts[t] = dtp[ro];
  }
#pragma unroll
  for (int it = 0; it < 16; it++) {
    int e = it * 256 + t;
    int j = e >> 6, cc = e & 63;
    const unsigned short* rowp = xcb + (size_t)j * CONVD;
    Xt[cc * 72 + j] = rowp[head * HDM + cc];
    Bs[j * 72 + cc] = rowp[768 + cc];
    Cs[j * 72 + cc] = rowp[832 + cc];
    Hs[j * 72 + cc] = f2bf(Hg[e]);          // Hg layout is [p][n]
  }
  __syncthreads();
  int lane = t & 63, w = t >> 6;
  int wr = (w >> 1) * 32, wc = (w & 1) * 32;
  int fl = lane & 15, kq = lane >> 4;
  int rbase = kq * 4, cl = fl;
  // ---- product 1: S_raw = C @ B^T (contract over n) ----
  f32x4 sacc[2][2];
#pragma unroll
  for (int i = 0; i < 2; i++)
#pragma unroll
    for (int j = 0; j < 2; j++) sacc[i][j] = (f32x4)0.f;
#pragma unroll
  for (int kk = 0; kk < 2; kk++) {
    short8 af[2], bfr[2];
#pragma unroll
    for (int mi = 0; mi < 2; mi++)
      af[mi] = *(const short8*)&Cs[(wr + mi * 16 + fl) * 72 + kk * 32 + kq * 8];
#pragma unroll
    for (int ni = 0; ni < 2; ni++)
      bfr[ni] = *(const short8*)&Bs[(wc + ni * 16 + fl) * 72 + kk * 32 + kq * 8];
#pragma unroll
    for (int mi = 0; mi < 2; mi++)
#pragma unroll
      for (int ni = 0; ni < 2; ni++)
        sacc[mi][ni] = __builtin_amdgcn_mfma_f32_16x16x32_bf16(af[mi], bfr[ni], sacc[mi][ni], 0, 0, 0);
  }
  __syncthreads();   // everyone done reading Cs/Bs fragments
  // ---- build S (mask j<=i, scale by dt[j]*exp(lc[i]-lc[j])); rescale C in place by exp(lc[i]) ----
#pragma unroll
  for (int mi = 0; mi < 2; mi++)
#pragma unroll
    for (int ni = 0; ni < 2; ni++)
#pragma unroll
      for (int r = 0; r < 4; r++) {
        int i = wr + mi * 16 + rbase + r;
        int j = wc + ni * 16 + cl;
        float v = (j <= i) ? sacc[mi][ni][r] * dts[j] * __expf(lcs[i] - lcs[j]) : 0.f;
        Ss[i * 72 + j] = f2bf(v);
      }
#pragma unroll
  for (int it = 0; it < 16; it++) {
    int e = it * 256 + t;
    int i = e >> 6, n = e & 63;
    float cv = bf2f(Cs[i * 72 + n]) * __expf(lcs[i]);
    Cs[i * 72 + n] = f2bf(cv);
  }
  __syncthreads();
  // ---- products 2+3 accumulated: Y = S @ X  +  C'' @ Hprev^T(layout) ----
  f32x4 yacc[2][2];
#pragma unroll
  for (int i = 0; i < 2; i++)
#pragma unroll
    for (int j = 0; j < 2; j++) yacc[i][j] = (f32x4)0.f;
#pragma unroll
  for (int kk = 0; kk < 2; kk++) {
    short8 af[2], bfr[2];
#pragma unroll
    for (int mi = 0; mi < 2; mi++)
      af[mi] = *(const short8*)&Ss[(wr + mi * 16 + fl) * 72 + kk * 32 + kq * 8];
#pragma unroll
    for (int ni = 0; ni < 2; ni++)
      bfr[ni] = *(const short8*)&Xt[(wc + ni * 16 + fl) * 72 + kk * 32 + kq * 8];
#pragma unroll
    for (int mi = 0; mi < 2; mi++)
#pragma unroll
      for (int ni = 0; ni < 2; ni++)
        yacc[mi][ni] = __builtin_amdgcn_mfma_f32_16x16x32_bf16(af[mi], bfr[ni], yacc[mi][ni], 0, 0, 0);
  }
#pragma unroll
  for (int kk = 0; kk < 2; kk++) {
    short8 af[2], bfr[2];
#pragma unroll
    for (int mi = 0; mi < 2; mi++)
      af[mi] = *(const short8*)&Cs[(wr + mi * 16 + fl) * 72 + kk * 32 + kq * 8];
#pragma unroll
    for (int ni = 0; ni < 2; ni++)
      bfr[ni] = *(const short8*)&Hs[(wc + ni * 16 + fl) * 72 + kk * 32 + kq * 8];
#pragma unroll
    for (int mi = 0; mi < 2; mi++)
#pragma unroll
      for (int ni = 0; ni < 2; ni++)
        yacc[mi][ni] = __builtin_amdgcn_mfma_f32_16x16x32_bf16(af[mi], bfr[ni], yacc[mi][ni], 0, 0, 0);
  }
  // ---- epilogue: + D * x, write bf16 ----
  float Dh = Dp[head];
  unsigned short* yb = Ybf + ((size_t)b * L_SEQ + l0) * DIN + head * HDM;
#pragma unroll
  for (int mi = 0; mi < 2; mi++)
#pragma unroll
    for (int ni = 0; ni < 2; ni++)
#pragma unroll
      for (int r = 0; r < 4; r++) {
        int i = wr + mi * 16 + rbase + r;
        int p = wc + ni * 16 + cl;
        float xval = bf2f(Xt[p * 72 + i]);
        yb[(size_t)i * DIN + p] = f2bf(yacc[mi][ni][r] + Dh * xval);
      }
}

// ---------------- gated RMS norm (bf16 y, bf16 z) ----------------
__global__ __launch_bounds__(256) void gate_rms_kernel(unsigned short* __restrict__ Y,
    const unsigned short* __restrict__ Z, const float* __restrict__ mw) {
  int wave = threadIdx.x >> 6, lane = threadIdx.x & 63;
  int row = blockIdx.x * 4 + wave;
  if (row >= NROWS) return;
  unsigned short* y = Y + (size_t)row * DIN;
  const unsigned short* z = Z + (size_t)row * DIN;
  float g[12];
  float ss = 0.f;
#pragma unroll
  for (int q = 0; q < 3; q++) {
    int c = q * 256 + lane * 4;
    uint2 yu = *(const uint2*)&y[c];
    uint2 zu = *(const uint2*)&z[c];
    float y0 = bf2f((unsigned short)(yu.x & 0xffff));
    float y1 = bf2f((unsigned short)(yu.x >> 16));
    float y2 = bf2f((unsigned short)(yu.y & 0xffff));
    float y3 = bf2f((unsigned short)(yu.y >> 16));
    float z0 = bf2f((unsigned short)(zu.x & 0xffff));
    float z1 = bf2f((unsigned short)(zu.x >> 16));
    float z2 = bf2f((unsigned short)(zu.y & 0xffff));
    float z3 = bf2f((unsigned short)(zu.y >> 16));
    float g0 = y0 * siluf(z0), g1 = y1 * siluf(z1);
    float g2 = y2 * siluf(z2), g3 = y3 * siluf(z3);
    ss += g0 * g0 + g1 * g1 + g2 * g2 + g3 * g3;
    g[q * 4 + 0] = g0; g[q * 4 + 1] = g1; g[q * 4 + 2] = g2; g[q * 4 + 3] = g3;
  }
#pragma unroll
  for (int o = 32; o > 0; o >>= 1) ss += __shfl_xor(ss, o, 64);
  float rs = rsqrtf(ss * (1.f / 768.f) + 1e-5f);
#pragma unroll
  for (int q = 0; q < 3; q++) {
    int c = q * 256 + lane * 4;
    float4 m = *(const float4*)&mw[c];
    uint2 pk;
    pk.x = pk_bf16(g[q*4+0] * rs * m.x, g[q*4+1] * rs * m.y);
    pk.y = pk_bf16(g[q*4+2] * rs * m.z, g[q*4+3] * rs * m.w);
    *(uint2*)&y[c] = pk;
  }
}

// ---------------- attention gate ----------------
__global__ __launch_bounds__(256) void attgate_kernel(const unsigned short* __restrict__ XN,
    const float* __restrict__ gw, const float* __restrict__ gb, float* __restrict__ G) {
  int wave = threadIdx.x >> 6, lane = threadIdx.x & 63;
  int row = blockIdx.x * 4 + wave;
  if (row >= NROWS) return;
  const unsigned short* x = XN + (size_t)row * CDIM;
  float acc[12] = {};
#pragma unroll
  for (int q = 0; q < 6; q++) {
    int k = q * 64 + lane;
    float xv = bf2f(x[k]);
    const float* wr = gw + (size_t)k * 12;
    float4 w0 = *(const float4*)&wr[0];
    float4 w1 = *(const float4*)&wr[4];
    float4 w2 = *(const float4*)&wr[8];
    acc[0] += xv * w0.x; acc[1] += xv * w0.y; acc[2]  += xv * w0.z; acc[3]  += xv * w0.w;
    acc[4] += xv * w1.x; acc[5] += xv * w1.y; acc[6]  += xv * w1.z; acc[7]  += xv * w1.w;
    acc[8] += xv * w2.x; acc[9] += xv * w2.y; acc[10] += xv * w2.z; acc[11] += xv * w2.w;
  }
#pragma unroll
  for (int h = 0; h < 12; h++)
#pragma unroll
    for (int o = 32; o > 0; o >>= 1) acc[h] += __shfl_xor(acc[h], o, 64);
  if (lane == 0) {
#pragma unroll
    for (int h = 0; h < 12; h++) {
      float v = acc[h] + gb[h];
      G[(size_t)row * 12 + h] = 1.f / (1.f + expf(-v));
    }
  }
}

// ---------------- windowed attention via MFMA: one wave per (window, head) ----------------
__global__ __launch_bounds__(64) void attn_kernel(const unsigned short* __restrict__ QKV,
    const float* __restrict__ G, unsigned short* __restrict__ XA) {
  __shared__ unsigned short Pl[64 * 72];   // P [i][j], row stride 72 (144B)
  __shared__ unsigned short Vt[32 * 72];   // V^T [d][j], slot-swizzled: slot' = (j>>3) ^ (d>>3)
  int blk = blockIdx.x;
  int head = blk % NHA;
  int win = blk / NHA;
  int b = win >> 6;
  int wrw = win & 63;
  int wy = wrw >> 3, wx = wrw & 7;
  int lane = threadIdx.x;
  int fl = lane & 15, kq = lane >> 4;
  const float scale = 0.17677669529663688f;
  size_t bbase = (size_t)b * L_SEQ;
  const unsigned short* qb = QKV + head * 32;

  short8 aq[4], bk[4];
#pragma unroll
  for (int ti = 0; ti < 4; ti++) {
    int tok = ti * 16 + fl; if (tok > 48) tok = 48;
    int iy = tok / 7, ix = tok - iy * 7;
    size_t r = bbase + (size_t)(wy * 7 + iy) * 56 + wx * 7 + ix;
    aq[ti] = *(const short8*)&qb[r * 1152 + kq * 8];
    bk[ti] = *(const short8*)&qb[r * 1152 + 384 + kq * 8];
  }
#pragma unroll
  for (int it = 0; it < 4; it++) {
    int j = (lane >> 2) + it * 16;
    int dc = (lane & 3) * 8;
    ushort8 v8 = (ushort8)0;
    if (j <= 48) {
      int iy = j / 7, ix = j - iy * 7;
      size_t r = bbase + (size_t)(wy * 7 + iy) * 56 + wx * 7 + ix;
      v8 = *(const ushort8*)&qb[r * 1152 + 768 + dc];
    }
#pragma unroll
    for (int q2 = 0; q2 < 8; q2++) {
      int d = dc + q2;
      Vt[d * 72 + (((j >> 3) ^ (d >> 3)) << 3) + (j & 7)] = v8[q2];
    }
  }
  f32x4 sacc[4][4];
#pragma unroll
  for (int tj = 0; tj < 4; tj++)
#pragma unroll
    for (int ti = 0; ti < 4; ti++)
      sacc[tj][ti] = __builtin_amdgcn_mfma_f32_16x16x32_bf16(bk[tj], aq[ti], (f32x4)0.f, 0, 0, 0);
#pragma unroll
  for (int ti = 0; ti < 4; ti++) {
    float mx = -1e30f;
#pragma unroll
    for (int tj = 0; tj < 4; tj++)
#pragma unroll
      for (int r = 0; r < 4; r++) {
        int j = tj * 16 + kq * 4 + r;
        float v = (j < 49) ? sacc[tj][ti][r] * scale : -1e30f;
        sacc[tj][ti][r] = v;
        mx = fmaxf(mx, v);
      }
    mx = fmaxf(mx, __shfl_xor(mx, 16, 64));
    mx = fmaxf(mx, __shfl_xor(mx, 32, 64));
    float sum = 0.f;
#pragma unroll
    for (int tj = 0; tj < 4; tj++)
#pragma unroll
      for (int r = 0; r < 4; r++) {
        float e = __expf(sacc[tj][ti][r] - mx);
        sacc[tj][ti][r] = e;
        sum += e;
      }
    sum += __shfl_xor(sum, 16, 64);
    sum += __shfl_xor(sum, 32, 64);
    float inv = 1.f / sum;
    int i = ti * 16 + fl;
#pragma unroll
    for (int tj = 0; tj < 4; tj++)
#pragma unroll
      for (int r = 0; r < 4; r++) {
        int j = tj * 16 + kq * 4 + r;
        Pl[i * 72 + j] = f2bf(sacc[tj][ti][r] * inv);
      }
  }
  f32x4 oacc[4][2];
#pragma unroll
  for (int i2 = 0; i2 < 4; i2++)
#pragma unroll
    for (int nd = 0; nd < 2; nd++) oacc[i2][nd] = (f32x4)0.f;
#pragma unroll
  for (int kk = 0; kk < 2; kk++) {
    short8 ap[4], bv[2];
#pragma unroll
    for (int i2 = 0; i2 < 4; i2++)
      ap[i2] = *(const short8*)&Pl[(i2 * 16 + fl) * 72 + kk * 32 + kq * 8];
#pragma unroll
    for (int nd = 0; nd < 2; nd++) {
      int d = nd * 16 + fl;
      bv[nd] = *(const short8*)&Vt[d * 72 + (((kk * 4 + kq) ^ (d >> 3)) << 3)];
    }
#pragma unroll
    for (int i2 = 0; i2 < 4; i2++)
#pragma unroll
      for (int nd = 0; nd < 2; nd++)
        oacc[i2][nd] = __builtin_amdgcn_mfma_f32_16x16x32_bf16(ap[i2], bv[nd], oacc[i2][nd], 0, 0, 0);
  }
#pragma unroll
  for (int i2 = 0; i2 < 4; i2++) {
#pragma unroll
    for (int r = 0; r < 4; r++) {
      int i = i2 * 16 + kq * 4 + r;
      if (i > 48) continue;
      int iy = i / 7, ix = i - iy * 7;
      size_t rg = bbase + (size_t)(wy * 7 + iy) * 56 + wx * 7 + ix;
      float g = G[rg * 12 + head];
#pragma unroll
      for (int nd = 0; nd < 2; nd++)
        XA[rg * CDIM + head * 32 + nd * 16 + fl] = f2bf(oacc[i2][nd][r] * g);
    }
  }
}

// ---------------- host launch ----------------
extern "C" void kernel_launch(void* const* d_in, const int* in_sizes, int n_in,
                              void* d_out, int out_size, void* d_ws, size_t ws_size,
                              hipStream_t stream) {
  const float* x        = (const float*)d_in[0];
  const float* norm1_w  = (const float*)d_in[1];
  const float* norm1_b  = (const float*)d_in[2];
  const float* W_in     = (const float*)d_in[3];
  const float* conv_w   = (const float*)d_in[4];
  const float* conv_b   = (const float*)d_in[5];
  const float* dt_bias  = (const float*)d_in[6];
  const float* A_log    = (const float*)d_in[7];
  const float* Dp       = (const float*)d_in[8];
  const float* mnorm_w  = (const float*)d_in[9];
  const float* W_out    = (const float*)d_in[10];
  const float* qkv_w    = (const float*)d_in[11];
  const float* qkv_b    = (const float*)d_in[12];
  const float* gate_w   = (const float*)d_in[13];
  const float* gate_b   = (const float*)d_in[14];
  const float* proj_w   = (const float*)d_in[15];
  const float* proj_b   = (const float*)d_in[16];
  const float* fusion_w = (const float*)d_in[17];
  const float* fusion_b = (const float*)d_in[18];
  const float* norm2_w  = (const float*)d_in[19];
  const float* norm2_b  = (const float*)d_in[20];
  const float* fc1_w    = (const float*)d_in[21];
  const float* fc1_b    = (const float*)d_in[22];
  const float* fc2_w    = (const float*)d_in[23];
  const float* fc2_b    = (const float*)d_in[24];
  float* OUT = (float*)d_out;

  float* ws = (float*)d_ws;
  unsigned short* XNBF = (unsigned short*)ws;              // 25088x384 bf16
  float* XC_  = ws + 4816896;                              // XC bf16; later CATBF+XABF
  float* SCR  = XC_ + 22478848;                            // ZX bf16 -> H fp32 -> z bf16 -> QKVbf -> M1bf
  unsigned short* YBF = (unsigned short*)(SCR + 22478848); // 25088x768 bf16
  unsigned short* WT  = (unsigned short*)(SCR + 22478848 + 9633792); // 3,047,424 bf16
  float* DT_ = (float*)(WT + 3047424);                     // 301,056
  float* DA_ = DT_ + 301056;                               // 301,056 (log-decay)
  float* G_  = DA_ + 301056;                               // 301,056
  float* QS_ = G_  + 301056;                               // 5,376 (need 4,704)

  unsigned short* ZXBF  = (unsigned short*)SCR;            // combined xBC+dt bf16 [25088][1024]
  unsigned short* XCBF  = (unsigned short*)XC_;            // conv output bf16 [25088][896]
  float* H_ = SCR;                                         // 96*49*4096 = 19,267,584 fl
  unsigned short* ZBF   = (unsigned short*)SCR;            // z bf16 (after H consumed)
  unsigned short* QKVBF = (unsigned short*)SCR;
  unsigned short* M1BF  = (unsigned short*)SCR;
  unsigned short* CATBF = (unsigned short*)XC_;
  unsigned short* XABF  = (unsigned short*)(XC_ + 9633792);

  unsigned short* wt_xbcdt = WT;           // 1024x384 (cols 768..1675 of W_in, padded)
  unsigned short* wt_z    = WT + 393216;   // 768x384
  unsigned short* wt_out  = WT + 688128;   // 384x768
  unsigned short* wt_qkv  = WT + 983040;   // 1152x384
  unsigned short* wt_proj = WT + 1425408;  // 384x384
  unsigned short* wt_fus  = WT + 1572864;  // 384x768
  unsigned short* wt_fc1  = WT + 1867776;  // 1536x384
  unsigned short* wt_fc2  = WT + 2457600;  // 384x1536

  wconv_kernel<<<dim3(12,  29), 256, 0, stream>>>(W_in + 768,  wt_xbcdt, 384, 908, DPROJ);
  wconv_kernel<<<dim3(12,  24), 256, 0, stream>>>(W_in,        wt_z,    384,  768, DPROJ);
  wconv_kernel<<<dim3(24,  12), 256, 0, stream>>>(W_out,       wt_out,  768,  384, 384);
  wconv_kernel<<<dim3(12,  36), 256, 0, stream>>>(qkv_w,       wt_qkv,  384, 1152, 1152);
  wconv_kernel<<<dim3(12,  12), 256, 0, stream>>>(proj_w,      wt_proj, 384,  384, 384);
  wconv_kernel<<<dim3(24,  12), 256, 0, stream>>>(fusion_w,    wt_fus,  768,  384, 384);
  wconv_kernel<<<dim3(12,  48), 256, 0, stream>>>(fc1_w,       wt_fc1,  384, 1536, 1536);
  wconv_kernel<<<dim3(48,  12), 256, 0, stream>>>(fc2_w,       wt_fc2, 1536,  384, 384);

  ln_kernel<<<6272, 256, 0, stream>>>(x, norm1_w, norm1_b, XNBF);

  // combined xBC+dt projection: [25088][908] -> ZXBF (ldc=1024)
  gemm_bf<0, false, false, true><<<dim3(8, 196), 256, 0, stream>>>(
      XNBF, wt_xbcdt, ZXBF, nullptr, nullptr, 0, NROWS, 908, CDIM, CDIM, ZXLD, 0);
  conv_bf_kernel<<<392, 256, 0, stream>>>(ZXBF, conv_w, conv_b, XCBF, ZXLD);
  dtprep_kernel<<<(NROWS * NHM + 255) / 256, 256, 0, stream>>>(ZXBF, dt_bias, A_log, DT_, DA_);

  mscan1_kernel<<<dim3(NCH, 96), 256, 0, stream>>>(XCBF, DT_, DA_, H_, QS_);
  scomb_kernel<<<dim3(96, 16), 64, 0, stream>>>(H_, QS_);
  mscan2_kernel<<<dim3(NCH, 96), 256, 0, stream>>>(XCBF, DT_, DA_, H_, Dp, YBF);

  gemm_bf<0, false, false, true><<<dim3(6, 196), 256, 0, stream>>>(
      XNBF, wt_z, ZBF, nullptr, nullptr, 0, NROWS, DIN, CDIM, CDIM, DIN, 0);
  gate_rms_kernel<<<6272, 256, 0, stream>>>(YBF, ZBF, mnorm_w);

  gemm_bf<0, false, false, true><<<dim3(3, 196), 256, 0, stream>>>(
      YBF, wt_out, CATBF, nullptr, nullptr, 0, NROWS, CDIM, DIN, DIN, 2 * CDIM, 0);

  attgate_kernel<<<6272, 256, 0, stream>>>(XNBF, gate_w, gate_b, G_);

  gemm_bf<0, true, false, true><<<dim3(9, 196), 256, 0, stream>>>(
      XNBF, wt_qkv, QKVBF, qkv_b, nullptr, 0, NROWS, 3 * CDIM, CDIM, CDIM, 3 * CDIM, 0);
  attn_kernel<<<512 * NHA, 64, 0, stream>>>(QKVBF, G_, XABF);

  gemm_bf<0, true, false, true><<<dim3(3, 196), 256, 0, stream>>>(
      XABF, wt_proj, CATBF, proj_b, nullptr, 0, NROWS, CDIM, CDIM, CDIM, 2 * CDIM, CDIM);

  gemm_bf<0, true, true, false><<<dim3(3, 196), 256, 0, stream>>>(
      CATBF, wt_fus, OUT, fusion_b, x, CDIM, NROWS, CDIM, 2 * CDIM, 2 * CDIM, CDIM, 0);

  ln_kernel<<<6272, 256, 0, stream>>>(OUT, norm2_w, norm2_b, XNBF);

  gemm_bf<1, true, false, true><<<dim3(12, 196), 256, 0, stream>>>(
      XNBF, wt_fc1, M1BF, fc1_b, nullptr, 0, NROWS, 4 * CDIM, CDIM, CDIM, 4 * CDIM, 0);
  gemm_bf<0, true, true, false><<<dim3(3, 196), 256, 0, stream>>>(
      M1BF, wt_fc2, OUT, fc2_b, OUT, CDIM, NROWS, CDIM, 4 * CDIM, 4 * CDIM, CDIM, 0);
}

// Round 9
// 653.342 us; speedup vs baseline: 1.0174x; 1.0045x over previous
//
#include <hip/hip_runtime.h>
#include <math.h>

static constexpr int L_SEQ  = 3136;
static constexpr int NBATCH = 8;
static constexpr int CDIM   = 384;
static constexpr int DIN    = 768;
static constexpr int NHM    = 12;
static constexpr int HDM    = 64;
static constexpr int DPROJ  = 1676;   // 2*768 + 2*64 + 12
static constexpr int CONVD  = 896;    // 768 + 128
static constexpr int NROWS  = NBATCH * L_SEQ; // 25088
static constexpr int NHA    = 12;
static constexpr int NCH    = 49;     // chunks per sequence
static constexpr int CHT    = 64;     // tokens per chunk (49*64 = 3136)
static constexpr int CTK    = 28;     // tokens per conv thread (3136/28 = 112)
static constexpr int ZXLD   = 1024;   // combined xBC+dt output stride (908 padded)
static constexpr int YAS    = 1152;   // concat [Y | XA] row stride

typedef __attribute__((ext_vector_type(8))) short short8;
typedef __attribute__((ext_vector_type(8))) unsigned short ushort8;
typedef __attribute__((ext_vector_type(4))) float f32x4;
typedef const unsigned int __attribute__((address_space(1)))* gua_t;
typedef unsigned int __attribute__((address_space(3)))* lua_t;

__device__ __forceinline__ float siluf(float x) { return x / (1.f + __expf(-x)); }
__device__ __forceinline__ unsigned short f2bf(float f) {
  unsigned int u = __float_as_uint(f);
  u += 0x7fff + ((u >> 16) & 1);
  return (unsigned short)(u >> 16);
}
__device__ __forceinline__ float bf2f(unsigned short h) {
  return __uint_as_float(((unsigned int)h) << 16);
}
// GELU via A&S 7.1.25 3-term erf (|err|<=2.5e-5, far below bf16 ulp)
__device__ __forceinline__ float geluf(float v) {
  float ax = fabsf(v) * 0.70710678118654752f;
  float t = __builtin_amdgcn_rcpf(fmaf(0.47047f, ax, 1.f));
  float p = t * fmaf(t, fmaf(t, 0.7478556f, -0.0958798f), 0.3480242f);
  float e = __expf(-ax * ax);
  float r = 1.f - p * e;
  float h = 0.5f * v;
  return fmaf(fabsf(h), r, h);
}
__device__ __forceinline__ unsigned int pk_bf16(float lo, float hi) {
  unsigned int d;
  asm("v_cvt_pk_bf16_f32 %0, %1, %2" : "=v"(d) : "v"(lo), "v"(hi));
  return d;
}

// ---------------- LayerNorm: one wave per row, C=384, bf16 out ----------------
__global__ __launch_bounds__(256) void ln_kernel(const float* __restrict__ in,
    const float* __restrict__ w, const float* __restrict__ b, unsigned short* __restrict__ out) {
  int wave = threadIdx.x >> 6, lane = threadIdx.x & 63;
  int row = blockIdx.x * 4 + wave;
  if (row >= NROWS) return;
  const float* r = in + (size_t)row * CDIM;
  float2 v[3];
  float s1 = 0.f, s2 = 0.f;
#pragma unroll
  for (int q = 0; q < 3; q++) {
    v[q] = *(const float2*)&r[q * 128 + lane * 2];
    s1 += v[q].x + v[q].y;
    s2 += v[q].x * v[q].x + v[q].y * v[q].y;
  }
#pragma unroll
  for (int o = 32; o > 0; o >>= 1) { s1 += __shfl_xor(s1, o, 64); s2 += __shfl_xor(s2, o, 64); }
  float mu = s1 * (1.f / 384.f);
  float var = s2 * (1.f / 384.f) - mu * mu;
  float rs = rsqrtf(var + 1e-5f);
  unsigned short* o = out + (size_t)row * CDIM;
#pragma unroll
  for (int q = 0; q < 3; q++) {
    int c = q * 128 + lane * 2;
    float2 wv = *(const float2*)&w[c];
    float2 bv = *(const float2*)&b[c];
    float ox = (v[q].x - mu) * rs * wv.x + bv.x;
    float oy = (v[q].y - mu) * rs * wv.y + bv.y;
    *(unsigned int*)&o[c] = pk_bf16(ox, oy);
  }
}

// ---------------- weight convert + transpose: W[K][N] fp32 -> WT[Np][K] bf16 ----------------
__global__ __launch_bounds__(256) void wconv_kernel(const float* __restrict__ W,
    unsigned short* __restrict__ WT, int K, int N, int ldw) {
  __shared__ float tile[32][33];
  int k0 = blockIdx.x * 32, n0 = blockIdx.y * 32;
  int tx = threadIdx.x & 31, ty = threadIdx.x >> 5;
#pragma unroll
  for (int j = 0; j < 4; j++) {
    int k = k0 + ty + j * 8;
    int n = n0 + tx;
    tile[ty + j * 8][tx] = (n < N) ? W[(size_t)k * ldw + n] : 0.f;
  }
  __syncthreads();
#pragma unroll
  for (int j = 0; j < 4; j++) {
    int n = n0 + ty + j * 8;
    int k = k0 + tx;
    WT[(size_t)n * K + k] = f2bf(tile[tx][ty + j * 8]);
  }
}

// ---------------- plain fp32 -> bf16 convert (no transpose) ----------------
__global__ void plainconv_kernel(const float* __restrict__ W, unsigned short* __restrict__ O, int n) {
  int i = blockIdx.x * 256 + threadIdx.x;
  if (i < n) O[i] = f2bf(W[i]);
}

// ---------------- combined bias: cb[n] = fusion_b[n] + sum_j proj_b[j]*fusion_w[384+j][n] ----------------
__global__ void biascomb_kernel(const float* __restrict__ fw, const float* __restrict__ fb,
    const float* __restrict__ pb, float* __restrict__ cb) {
  int n = blockIdx.x * 256 + threadIdx.x;
  if (n >= 384) return;
  float a = fb[n];
  for (int j = 0; j < 384; j++) a += pb[j] * fw[(size_t)(384 + j) * 384 + n];
  cb[n] = a;
}

// ---------------- bf16 MFMA GEMM: 3-buffer depth-2 counted-vmcnt pipeline,
// ---------------- slot-XOR LDS swizzle, XCD swizzle, transposed acc + swizzled LDS-bounce epilogue
template<int ACT, bool HASBIAS, bool HASRES, bool OUTBF>
__global__ __launch_bounds__(256, 4) void gemm_bf(
    const unsigned short* __restrict__ A, const unsigned short* __restrict__ WT,
    void* __restrict__ Cp, const float* __restrict__ bias,
    const float* __restrict__ res, int ldr,
    int M, int N, int K, int lda, int ldc, int coff)
{
  __shared__ unsigned short SMEM[24576];   // A bufs @ {0,4096,8192}, W bufs @ {12288,+4096,+8192}; reused as bounce
  int t = threadIdx.x;
  // XCD-aware bijective remap (m204)
  int gx = gridDim.x;
  int nwg = gx * gridDim.y;
  int orig = blockIdx.y * gx + blockIdx.x;
  int qq = nwg >> 3, rr = nwg & 7;
  int xcd = orig & 7, seq = orig >> 3;
  int wgid = (xcd < rr ? xcd * (qq + 1) : rr * (qq + 1) + (xcd - rr) * qq) + seq;
  int m0 = (wgid / gx) * 128, n0 = (wgid % gx) * 128;

  int lane = t & 63, w = t >> 6;
  int wr = (w >> 1) * 64, wc = (w & 1) * 64;
  int fl = lane & 15, kq = lane >> 4;
  int so = (kq ^ ((lane >> 1) & 3)) * 8;   // swizzled 16B slot for ds_read

  int srow = t >> 2, sq = t & 3;
  int q0 = sq ^ ((srow >> 1) & 3);
  const unsigned short* pA0 = A  + (size_t)(m0 + srow) * lda + q0 * 8;
  const unsigned short* pA1 = A  + (size_t)(m0 + 64 + srow) * lda + q0 * 8;
  const unsigned short* pW0 = WT + (size_t)(n0 + srow) * K + q0 * 8;
  const unsigned short* pW1 = WT + (size_t)(n0 + 64 + srow) * K + q0 * 8;

  f32x4 acc[4][4];     // transposed: acc[mi][ni] regs = n (kq*4+r), lanes = m (fl)
#pragma unroll
  for (int i = 0; i < 4; i++)
#pragma unroll
    for (int j = 0; j < 4; j++) acc[i][j] = (f32x4)0.f;

  auto STAGE = [&](int buf) {
    unsigned short* as = SMEM + buf * 4096;
    unsigned short* ws = SMEM + 12288 + buf * 4096;
    __builtin_amdgcn_global_load_lds((gua_t)pA0, (lua_t)as + t * 4, 16, 0, 0);
    __builtin_amdgcn_global_load_lds((gua_t)pA1, (lua_t)(as + 2048) + t * 4, 16, 0, 0);
    __builtin_amdgcn_global_load_lds((gua_t)pW0, (lua_t)ws + t * 4, 16, 0, 0);
    __builtin_amdgcn_global_load_lds((gua_t)pW1, (lua_t)(ws + 2048) + t * 4, 16, 0, 0);
    pA0 += 32; pA1 += 32; pW0 += 32; pW1 += 32;
  };

  int nk = K >> 5;               // all K here are >= 64, so nk >= 2
  STAGE(0);
  STAGE(1);
  int cb = 0, sb = 2;
  for (int ks = 0; ks < nk; ks++) {
    if (ks + 1 < nk) {
      asm volatile("s_waitcnt vmcnt(4)" ::: "memory");   // tile ks landed; tile ks+1 stays in flight
    } else {
      asm volatile("s_waitcnt vmcnt(0)" ::: "memory");
    }
    __builtin_amdgcn_s_barrier();
    asm volatile("" ::: "memory");
    __builtin_amdgcn_sched_barrier(0);
    if (ks + 2 < nk) {           // buffer sb's readers (tile ks-1) drained at the barrier above
      STAGE(sb);
      sb = sb == 2 ? 0 : sb + 1;
    }
    const unsigned short* as = SMEM + cb * 4096;
    const unsigned short* ws = SMEM + 12288 + cb * 4096;
    cb = cb == 2 ? 0 : cb + 1;
    short8 af[4], bfr[4];
#pragma unroll
    for (int mi = 0; mi < 4; mi++) af[mi] = *(const short8*)&as[(wr + mi * 16 + fl) * 32 + so];
#pragma unroll
    for (int ni = 0; ni < 4; ni++) bfr[ni] = *(const short8*)&ws[(wc + ni * 16 + fl) * 32 + so];
    // swapped operands: output rows = n (from W frag), cols = m (from A frag)
#pragma unroll
    for (int mi = 0; mi < 4; mi++)
#pragma unroll
      for (int ni = 0; ni < 4; ni++)
        acc[mi][ni] = __builtin_amdgcn_mfma_f32_16x16x32_bf16(bfr[ni], af[mi], acc[mi][ni], 0, 0, 0);
  }
  // epilogue: lane holds m = wr+mi*16+fl, n = wc+ni*16+kq*4+{0..3}
  if (OUTBF) {
    __syncthreads();   // reuse SMEM as 128x128 bf16 bounce tile (granule-XOR swizzled)
    float4 bv[4];
    if (HASBIAS) {
#pragma unroll
      for (int ni = 0; ni < 4; ni++) bv[ni] = *(const float4*)&bias[n0 + wc + ni * 16 + kq * 4];
    }
#pragma unroll
    for (int mi = 0; mi < 4; mi++) {
      int mloc = wr + mi * 16 + fl;
#pragma unroll
      for (int ni = 0; ni < 4; ni++) {
        float v0 = acc[mi][ni][0], v1 = acc[mi][ni][1];
        float v2 = acc[mi][ni][2], v3 = acc[mi][ni][3];
        if (HASBIAS) { v0 += bv[ni].x; v1 += bv[ni].y; v2 += bv[ni].z; v3 += bv[ni].w; }
        if (ACT == 1) { v0 = geluf(v0); v1 = geluf(v1); v2 = geluf(v2); v3 = geluf(v3); }
        int gidx = (wc >> 2) + ni * 4 + kq;          // 8B granule index in row (0..31)
        int gs = gidx ^ (mloc & 15);                 // bank-spread swizzle
        uint2 pk; pk.x = pk_bf16(v0, v1); pk.y = pk_bf16(v2, v3);
        *(uint2*)&SMEM[mloc * 128 + gs * 4] = pk;
      }
    }
    __syncthreads();
    unsigned short* outp = (unsigned short*)Cp + coff + n0;
#pragma unroll
    for (int it2 = 0; it2 < 16; it2++) {
      int gg = it2 * 256 + t;
      int row = gg >> 5, g = gg & 31;
      uint2 v = *(const uint2*)&SMEM[row * 128 + (g ^ (row & 15)) * 4];
      *(uint2*)&outp[(size_t)(m0 + row) * ldc + g * 4] = v;
    }
  } else {
    int rbase = kq * 4;
    float* outp = (float*)Cp + coff;
#pragma unroll
    for (int mi = 0; mi < 4; mi++) {
      int m = m0 + wr + mi * 16 + fl;
      float* rowp = outp + (size_t)m * ldc + n0;
#pragma unroll
      for (int ni = 0; ni < 4; ni++) {
        int nb = wc + ni * 16 + rbase;
        float4 v;
        v.x = acc[mi][ni][0]; v.y = acc[mi][ni][1];
        v.z = acc[mi][ni][2]; v.w = acc[mi][ni][3];
        if (HASBIAS) {
          float4 bvv = *(const float4*)&bias[n0 + nb];
          v.x += bvv.x; v.y += bvv.y; v.z += bvv.z; v.w += bvv.w;
        }
        if (ACT == 1) { v.x = geluf(v.x); v.y = geluf(v.y); v.z = geluf(v.z); v.w = geluf(v.w); }
        if (HASRES) {
          float4 rv = *(const float4*)&res[(size_t)m * ldr + n0 + nb];
          v.x += rv.x; v.y += rv.y; v.z += rv.z; v.w += rv.w;
        }
        *(float4*)&rowp[nb] = v;
      }
    }
  }
}

// ---------------- dt prep: read bf16 dt slice of combined ZX; DA holds LOG-decay ----------------
__global__ void dtprep_kernel(const unsigned short* __restrict__ ZX, const float* __restrict__ dt_bias,
    const float* __restrict__ A_log, float* __restrict__ DT, float* __restrict__ DA) {
  int idx = blockIdx.x * blockDim.x + threadIdx.x;
  if (idx >= NROWS * NHM) return;
  int h = idx % NHM;
  int row = idx / NHM;
  float v = bf2f(ZX[(size_t)row * ZXLD + 896 + h]) + dt_bias[h];
  float sp = (v > 20.f) ? v : log1pf(expf(v));
  DT[idx] = sp;
  DA[idx] = -expf(A_log[h]) * sp;   // log of decay (<= 0)
}

// ---------------- depthwise causal conv (k=4) + bias + silu; bf16 in/out, reg shift history ----------------
__global__ __launch_bounds__(256) void conv_bf_kernel(const unsigned short* __restrict__ xbc,
    const float* __restrict__ cw, const float* __restrict__ cb, unsigned short* __restrict__ XC,
    int ldin) {
  int t = blockIdx.x * 256 + threadIdx.x;
  int c8 = t % 112;                 // 8-channel group within row (112*8 = 896)
  int rg = t / 112;                 // b * 112 + lchunk
  int b = rg / 112, lc = rg % 112;
  int l0 = lc * CTK;
  int c0 = c8 * 8;
  float w0[8], w1[8], w2[8], w3[8], bq[8];
#pragma unroll
  for (int i = 0; i < 8; i++) {
    bq[i] = cb[c0 + i];
    float4 w4 = *(const float4*)&cw[(c0 + i) * 4];
    w0[i] = w4.x; w1[i] = w4.y; w2[i] = w4.z; w3[i] = w4.w;
  }
  const unsigned short* base = xbc + (size_t)b * L_SEQ * ldin + c0;
  unsigned short* obase = XC + (size_t)b * L_SEQ * CONVD + c0;
  ushort8 h0 = (ushort8)0, h1 = (ushort8)0, h2 = (ushort8)0;
  if (l0 >= 3) {
    h0 = *(const ushort8*)&base[(size_t)(l0 - 3) * ldin];
    h1 = *(const ushort8*)&base[(size_t)(l0 - 2) * ldin];
    h2 = *(const ushort8*)&base[(size_t)(l0 - 1) * ldin];
  }
  for (int i = 0; i < CTK; i++) {
    ushort8 cur = *(const ushort8*)&base[(size_t)(l0 + i) * ldin];
    ushort8 ov;
#pragma unroll
    for (int q = 0; q < 8; q++) {
      float acc = bq[q] + w0[q] * bf2f(h0[q]) + w1[q] * bf2f(h1[q])
                + w2[q] * bf2f(h2[q]) + w3[q] * bf2f(cur[q]);
      ov[q] = f2bf(siluf(acc));
    }
    *(ushort8*)&obase[(size_t)(l0 + i) * CONVD] = ov;
    h0 = h1; h1 = h2; h2 = cur;
  }
}

// ---------------- chunked SSD scan pass 1 (MFMA): G^T[p][n] = sum_j X[j][p] * (B[j][n]*w[j]) ----------------
__global__ __launch_bounds__(256) void mscan1_kernel(const unsigned short* __restrict__ XC,
    const float* __restrict__ dtp, const float* __restrict__ dta,
    float* __restrict__ H, float* __restrict__ QS) {
  __shared__ unsigned short Xt[64 * 72];   // X^T [p][j]
  __shared__ unsigned short Bt[64 * 72];   // (B*w)^T [n][j]
  __shared__ float lcs[64];
  __shared__ float wss[64];
  int ch = blockIdx.x, bh = blockIdx.y;
  int b = bh / NHM, head = bh - b * NHM;
  int t = threadIdx.x;
  int l0 = ch * CHT;
  const unsigned short* xcb = XC + ((size_t)b * L_SEQ + l0) * CONVD;
  if (t < 64) {
    size_t ro = ((size_t)b * L_SEQ + l0 + t) * NHM + head;
    float s = dta[ro];
#pragma unroll
    for (int o = 1; o < 64; o <<= 1) {
      float u = __shfl_up(s, o, 64);
      if (t >= o) s += u;
    }
    float lc63 = __shfl(s, 63, 64);
    lcs[t] = s;
    wss[t] = dtp[ro] * __expf(lc63 - s);
    if (t == 63) QS[bh * NCH + ch] = __expf(s);
  }
  __syncthreads();
#pragma unroll
  for (int it = 0; it < 16; it++) {
    int e = it * 256 + t;
    int j = e >> 6, cc = e & 63;
    const unsigned short* rowp = xcb + (size_t)j * CONVD;
    Xt[cc * 72 + j] = rowp[head * HDM + cc];
    Bt[cc * 72 + j] = f2bf(bf2f(rowp[768 + cc]) * wss[j]);
  }
  __syncthreads();
  int lane = t & 63, w = t >> 6;
  int wr = (w >> 1) * 32, wc = (w & 1) * 32;
  int fl = lane & 15, kq = lane >> 4;
  f32x4 acc[2][2];
#pragma unroll
  for (int i = 0; i < 2; i++)
#pragma unroll
    for (int j = 0; j < 2; j++) acc[i][j] = (f32x4)0.f;
#pragma unroll
  for (int kk = 0; kk < 2; kk++) {
    short8 af[2], bfr[2];
#pragma unroll
    for (int mi = 0; mi < 2; mi++)
      af[mi] = *(const short8*)&Xt[(wr + mi * 16 + fl) * 72 + kk * 32 + kq * 8];
#pragma unroll
    for (int ni = 0; ni < 2; ni++)
      bfr[ni] = *(const short8*)&Bt[(wc + ni * 16 + fl) * 72 + kk * 32 + kq * 8];
#pragma unroll
    for (int mi = 0; mi < 2; mi++)
#pragma unroll
      for (int ni = 0; ni < 2; ni++)
        acc[mi][ni] = __builtin_amdgcn_mfma_f32_16x16x32_bf16(af[mi], bfr[ni], acc[mi][ni], 0, 0, 0);
  }
  float* Hp = H + ((size_t)bh * NCH + ch) * 4096;
  int rbase = kq * 4, cl = fl;
#pragma unroll
  for (int mi = 0; mi < 2; mi++)
#pragma unroll
    for (int ni = 0; ni < 2; ni++)
#pragma unroll
      for (int r = 0; r < 4; r++)
        Hp[(size_t)(wr + mi * 16 + rbase + r) * 64 + wc + ni * 16 + cl] = acc[mi][ni][r];
}

// ---------------- scan combine (exclusive prefix over chunks) ----------------
__global__ __launch_bounds__(64) void scomb_kernel(float* __restrict__ H,
    const float* __restrict__ QS) {
  int bh = blockIdx.x;
  int e = (blockIdx.y * 64 + threadIdx.x) * 4;
  float4 cur = make_float4(0.f, 0.f, 0.f, 0.f);
  for (int s = 0; s < NCH; s++) {
    float* Hp = H + ((size_t)bh * NCH + s) * 4096 + e;
    float q = QS[bh * NCH + s];
    float4 tmp = *(float4*)Hp;
    *(float4*)Hp = cur;
    cur.x = q * cur.x + tmp.x;
    cur.y = q * cur.y + tmp.y;
    cur.z = q * cur.z + tmp.z;
    cur.w = q * cur.w + tmp.w;
  }
}

// ---------------- chunked SSD scan pass 2 (MFMA); writes Y into YA cols 0..767 ----------------
__global__ __launch_bounds__(256) void mscan2_kernel(const unsigned short* __restrict__ XC,
    const float* __restrict__ dtp, const float* __restrict__ dta,
    const float* __restrict__ H, const float* __restrict__ Dp,
    unsigned short* __restrict__ Ybf) {
  __shared__ unsigned short Cs[64 * 72];   // C [i][n] (later scaled by exp(lc[i]))
  __shared__ unsigned short Bs[64 * 72];   // B [j][n]
  __shared__ unsigned short Xt[64 * 72];   // X^T [p][j]
  __shared__ unsigned short Hs[64 * 72];   // Hprev [p][n]
  __shared__ unsigned short Ss[64 * 72];   // S [i][j] masked+scaled
  __shared__ float lcs[64];
  __shared__ float dts[64];
  int ch = blockIdx.x, bh = blockIdx.y;
  int b = bh / NHM, head = bh - b * NHM;
  int t = threadIdx.x;
  int l0 = ch * CHT;
  const unsigned short* xcb = XC + ((size_t)b * L_SEQ + l0) * CONVD;
  const float* Hg = H + ((size_t)bh * NCH + ch) * 4096;
  if (t < 64) {
    size_t ro = ((size_t)b * L_SEQ + l0 + t) * NHM + head;
    float s = dta[ro];
#pragma unroll
    for (int o = 1; o < 64; o <<= 1) {
      float u = __shfl_up(s, o, 64);
      if (t >= o) s += u;
    }
    lcs[t] = s;
    dts[t] = dtp[ro];
  }
#pragma unroll
  for (int it = 0; it < 16; it++) {
    int e = it * 256 + t;
    int j = e >> 6, cc = e & 63;
    const unsigned short* rowp = xcb + (size_t)j * CONVD;
    Xt[cc * 72 + j] = rowp[head * HDM + cc];
    Bs[j * 72 + cc] = rowp[768 + cc];
    Cs[j * 72 + cc] = rowp[832 + cc];
    Hs[j * 72 + cc] = f2bf(Hg[e]);          // Hg layout is [p][n]
  }
  __syncthreads();
  int lane = t & 63, w = t >> 6;
  int wr = (w >> 1) * 32, wc = (w & 1) * 32;
  int fl = lane & 15, kq = lane >> 4;
  int rbase = kq * 4, cl = fl;
  // ---- product 1: S_raw = C @ B^T (contract over n) ----
  f32x4 sacc[2][2];
#pragma unroll
  for (int i = 0; i < 2; i++)
#pragma unroll
    for (int j = 0; j < 2; j++) sacc[i][j] = (f32x4)0.f;
#pragma unroll
  for (int kk = 0; kk < 2; kk++) {
    short8 af[2], bfr[2];
#pragma unroll
    for (int mi = 0; mi < 2; mi++)
      af[mi] = *(const short8*)&Cs[(wr + mi * 16 + fl) * 72 + kk * 32 + kq * 8];
#pragma unroll
    for (int ni = 0; ni < 2; ni++)
      bfr[ni] = *(const short8*)&Bs[(wc + ni * 16 + fl) * 72 + kk * 32 + kq * 8];
#pragma unroll
    for (int mi = 0; mi < 2; mi++)
#pragma unroll
      for (int ni = 0; ni < 2; ni++)
        sacc[mi][ni] = __builtin_amdgcn_mfma_f32_16x16x32_bf16(af[mi], bfr[ni], sacc[mi][ni], 0, 0, 0);
  }
  __syncthreads();   // everyone done reading Cs/Bs fragments
  // ---- build S (mask j<=i, scale by dt[j]*exp(lc[i]-lc[j])); rescale C in place by exp(lc[i]) ----
#pragma unroll
  for (int mi = 0; mi < 2; mi++)
#pragma unroll
    for (int ni = 0; ni < 2; ni++)
#pragma unroll
      for (int r = 0; r < 4; r++) {
        int i = wr + mi * 16 + rbase + r;
        int j = wc + ni * 16 + cl;
        float v = (j <= i) ? sacc[mi][ni][r] * dts[j] * __expf(lcs[i] - lcs[j]) : 0.f;
        Ss[i * 72 + j] = f2bf(v);
      }
#pragma unroll
  for (int it = 0; it < 16; it++) {
    int e = it * 256 + t;
    int i = e >> 6, n = e & 63;
    float cv = bf2f(Cs[i * 72 + n]) * __expf(lcs[i]);
    Cs[i * 72 + n] = f2bf(cv);
  }
  __syncthreads();
  // ---- products 2+3 accumulated: Y = S @ X  +  C'' @ Hprev^T(layout) ----
  f32x4 yacc[2][2];
#pragma unroll
  for (int i = 0; i < 2; i++)
#pragma unroll
    for (int j = 0; j < 2; j++) yacc[i][j] = (f32x4)0.f;
#pragma unroll
  for (int kk = 0; kk < 2; kk++) {
    short8 af[2], bfr[2];
#pragma unroll
    for (int mi = 0; mi < 2; mi++)
      af[mi] = *(const short8*)&Ss[(wr + mi * 16 + fl) * 72 + kk * 32 + kq * 8];
#pragma unroll
    for (int ni = 0; ni < 2; ni++)
      bfr[ni] = *(const short8*)&Xt[(wc + ni * 16 + fl) * 72 + kk * 32 + kq * 8];
#pragma unroll
    for (int mi = 0; mi < 2; mi++)
#pragma unroll
      for (int ni = 0; ni < 2; ni++)
        yacc[mi][ni] = __builtin_amdgcn_mfma_f32_16x16x32_bf16(af[mi], bfr[ni], yacc[mi][ni], 0, 0, 0);
  }
#pragma unroll
  for (int kk = 0; kk < 2; kk++) {
    short8 af[2], bfr[2];
#pragma unroll
    for (int mi = 0; mi < 2; mi++)
      af[mi] = *(const short8*)&Cs[(wr + mi * 16 + fl) * 72 + kk * 32 + kq * 8];
#pragma unroll
    for (int ni = 0; ni < 2; ni++)
      bfr[ni] = *(const short8*)&Hs[(wc + ni * 16 + fl) * 72 + kk * 32 + kq * 8];
#pragma unroll
    for (int mi = 0; mi < 2; mi++)
#pragma unroll
      for (int ni = 0; ni < 2; ni++)
        yacc[mi][ni] = __builtin_amdgcn_mfma_f32_16x16x32_bf16(af[mi], bfr[ni], yacc[mi][ni], 0, 0, 0);
  }
  // ---- epilogue: + D * x, write bf16 into YA (stride YAS) ----
  float Dh = Dp[head];
  unsigned short* yb = Ybf + ((size_t)b * L_SEQ + l0) * YAS + head * HDM;
#pragma unroll
  for (int mi = 0; mi < 2; mi++)
#pragma unroll
    for (int ni = 0; ni < 2; ni++)
#pragma unroll
      for (int r = 0; r < 4; r++) {
        int i = wr + mi * 16 + rbase + r;
        int p = wc + ni * 16 + cl;
        float xval = bf2f(Xt[p * 72 + i]);
        yb[(size_t)i * YAS + p] = f2bf(yacc[mi][ni][r] + Dh * xval);
      }
}

// ---------------- gated RMS norm in-place on YA cols 0..767 (bf16 y, bf16 z) ----------------
__global__ __launch_bounds__(256) void gate_rms_kernel(unsigned short* __restrict__ Y,
    const unsigned short* __restrict__ Z, const float* __restrict__ mw) {
  int wave = threadIdx.x >> 6, lane = threadIdx.x & 63;
  int row = blockIdx.x * 4 + wave;
  if (row >= NROWS) return;
  unsigned short* y = Y + (size_t)row * YAS;
  const unsigned short* z = Z + (size_t)row * DIN;
  float g[12];
  float ss = 0.f;
#pragma unroll
  for (int q = 0; q < 3; q++) {
    int c = q * 256 + lane * 4;
    uint2 yu = *(const uint2*)&y[c];
    uint2 zu = *(const uint2*)&z[c];
    float y0 = bf2f((unsigned short)(yu.x & 0xffff));
    float y1 = bf2f((unsigned short)(yu.x >> 16));
    float y2 = bf2f((unsigned short)(yu.y & 0xffff));
    float y3 = bf2f((unsigned short)(yu.y >> 16));
    float z0 = bf2f((unsigned short)(zu.x & 0xffff));
    float z1 = bf2f((unsigned short)(zu.x >> 16));
    float z2 = bf2f((unsigned short)(zu.y & 0xffff));
    float z3 = bf2f((unsigned short)(zu.y >> 16));
    float g0 = y0 * siluf(z0), g1 = y1 * siluf(z1);
    float g2 = y2 * siluf(z2), g3 = y3 * siluf(z3);
    ss += g0 * g0 + g1 * g1 + g2 * g2 + g3 * g3;
    g[q * 4 + 0] = g0; g[q * 4 + 1] = g1; g[q * 4 + 2] = g2; g[q * 4 + 3] = g3;
  }
#pragma unroll
  for (int o = 32; o > 0; o >>= 1) ss += __shfl_xor(ss, o, 64);
  float rs = rsqrtf(ss * (1.f / 768.f) + 1e-5f);
#pragma unroll
  for (int q = 0; q < 3; q++) {
    int c = q * 256 + lane * 4;
    float4 m = *(const float4*)&mw[c];
    uint2 pk;
    pk.x = pk_bf16(g[q*4+0] * rs * m.x, g[q*4+1] * rs * m.y);
    pk.y = pk_bf16(g[q*4+2] * rs * m.z, g[q*4+3] * rs * m.w);
    *(uint2*)&y[c] = pk;
  }
}

// ---------------- attention gate ----------------
__global__ __launch_bounds__(256) void attgate_kernel(const unsigned short* __restrict__ XN,
    const float* __restrict__ gw, const float* __restrict__ gb, float* __restrict__ G) {
  int wave = threadIdx.x >> 6, lane = threadIdx.x & 63;
  int row = blockIdx.x * 4 + wave;
  if (row >= NROWS) return;
  const unsigned short* x = XN + (size_t)row * CDIM;
  float acc[12] = {};
#pragma unroll
  for (int q = 0; q < 6; q++) {
    int k = q * 64 + lane;
    float xv = bf2f(x[k]);
    const float* wr = gw + (size_t)k * 12;
    float4 w0 = *(const float4*)&wr[0];
    float4 w1 = *(const float4*)&wr[4];
    float4 w2 = *(const float4*)&wr[8];
    acc[0] += xv * w0.x; acc[1] += xv * w0.y; acc[2]  += xv * w0.z; acc[3]  += xv * w0.w;
    acc[4] += xv * w1.x; acc[5] += xv * w1.y; acc[6]  += xv * w1.z; acc[7]  += xv * w1.w;
    acc[8] += xv * w2.x; acc[9] += xv * w2.y; acc[10] += xv * w2.z; acc[11] += xv * w2.w;
  }
#pragma unroll
  for (int h = 0; h < 12; h++)
#pragma unroll
    for (int o = 32; o > 0; o >>= 1) acc[h] += __shfl_xor(acc[h], o, 64);
  if (lane == 0) {
#pragma unroll
    for (int h = 0; h < 12; h++) {
      float v = acc[h] + gb[h];
      G[(size_t)row * 12 + h] = 1.f / (1.f + expf(-v));
    }
  }
}

// ---------------- windowed attention via MFMA; writes gated out into YA cols 768..1151 ----------------
__global__ __launch_bounds__(64) void attn_kernel(const unsigned short* __restrict__ QKV,
    const float* __restrict__ G, unsigned short* __restrict__ YA) {
  __shared__ unsigned short Pl[64 * 72];   // P [i][j], row stride 72 (144B)
  __shared__ unsigned short Vt[32 * 72];   // V^T [d][j], slot-swizzled: slot' = (j>>3) ^ (d>>3)
  int blk = blockIdx.x;
  int head = blk % NHA;
  int win = blk / NHA;
  int b = win >> 6;
  int wrw = win & 63;
  int wy = wrw >> 3, wx = wrw & 7;
  int lane = threadIdx.x;
  int fl = lane & 15, kq = lane >> 4;
  const float scale = 0.17677669529663688f;
  size_t bbase = (size_t)b * L_SEQ;
  const unsigned short* qb = QKV + head * 32;

  short8 aq[4], bk[4];
#pragma unroll
  for (int ti = 0; ti < 4; ti++) {
    int tok = ti * 16 + fl; if (tok > 48) tok = 48;
    int iy = tok / 7, ix = tok - iy * 7;
    size_t r = bbase + (size_t)(wy * 7 + iy) * 56 + wx * 7 + ix;
    aq[ti] = *(const short8*)&qb[r * 1152 + kq * 8];
    bk[ti] = *(const short8*)&qb[r * 1152 + 384 + kq * 8];
  }
#pragma unroll
  for (int it = 0; it < 4; it++) {
    int j = (lane >> 2) + it * 16;
    int dc = (lane & 3) * 8;
    ushort8 v8 = (ushort8)0;
    if (j <= 48) {
      int iy = j / 7, ix = j - iy * 7;
      size_t r = bbase + (size_t)(wy * 7 + iy) * 56 + wx * 7 + ix;
      v8 = *(const ushort8*)&qb[r * 1152 + 768 + dc];
    }
#pragma unroll
    for (int q2 = 0; q2 < 8; q2++) {
      int d = dc + q2;
      Vt[d * 72 + (((j >> 3) ^ (d >> 3)) << 3) + (j & 7)] = v8[q2];
    }
  }
  f32x4 sacc[4][4];
#pragma unroll
  for (int tj = 0; tj < 4; tj++)
#pragma unroll
    for (int ti = 0; ti < 4; ti++)
      sacc[tj][ti] = __builtin_amdgcn_mfma_f32_16x16x32_bf16(bk[tj], aq[ti], (f32x4)0.f, 0, 0, 0);
#pragma unroll
  for (int ti = 0; ti < 4; ti++) {
    float mx = -1e30f;
#pragma unroll
    for (int tj = 0; tj < 4; tj++)
#pragma unroll
      for (int r = 0; r < 4; r++) {
        int j = tj * 16 + kq * 4 + r;
        float v = (j < 49) ? sacc[tj][ti][r] * scale : -1e30f;
        sacc[tj][ti][r] = v;
        mx = fmaxf(mx, v);
      }
    mx = fmaxf(mx, __shfl_xor(mx, 16, 64));
    mx = fmaxf(mx, __shfl_xor(mx, 32, 64));
    float sum = 0.f;
#pragma unroll
    for (int tj = 0; tj < 4; tj++)
#pragma unroll
      for (int r = 0; r < 4; r++) {
        float e = __expf(sacc[tj][ti][r] - mx);
        sacc[tj][ti][r] = e;
        sum += e;
      }
    sum += __shfl_xor(sum, 16, 64);
    sum += __shfl_xor(sum, 32, 64);
    float inv = 1.f / sum;
    int i = ti * 16 + fl;
#pragma unroll
    for (int tj = 0; tj < 4; tj++)
#pragma unroll
      for (int r = 0; r < 4; r++) {
        int j = tj * 16 + kq * 4 + r;
        Pl[i * 72 + j] = f2bf(sacc[tj][ti][r] * inv);
      }
  }
  f32x4 oacc[4][2];
#pragma unroll
  for (int i2 = 0; i2 < 4; i2++)
#pragma unroll
    for (int nd = 0; nd < 2; nd++) oacc[i2][nd] = (f32x4)0.f;
#pragma unroll
  for (int kk = 0; kk < 2; kk++) {
    short8 ap[4], bv[2];
#pragma unroll
    for (int i2 = 0; i2 < 4; i2++)
      ap[i2] = *(const short8*)&Pl[(i2 * 16 + fl) * 72 + kk * 32 + kq * 8];
#pragma unroll
    for (int nd = 0; nd < 2; nd++) {
      int d = nd * 16 + fl;
      bv[nd] = *(const short8*)&Vt[d * 72 + (((kk * 4 + kq) ^ (d >> 3)) << 3)];
    }
#pragma unroll
    for (int i2 = 0; i2 < 4; i2++)
#pragma unroll
      for (int nd = 0; nd < 2; nd++)
        oacc[i2][nd] = __builtin_amdgcn_mfma_f32_16x16x32_bf16(ap[i2], bv[nd], oacc[i2][nd], 0, 0, 0);
  }
#pragma unroll
  for (int i2 = 0; i2 < 4; i2++) {
#pragma unroll
    for (int r = 0; r < 4; r++) {
      int i = i2 * 16 + kq * 4 + r;
      if (i > 48) continue;
      int iy = i / 7, ix = i - iy * 7;
      size_t rg = bbase + (size_t)(wy * 7 + iy) * 56 + wx * 7 + ix;
      float g = G[rg * 12 + head];
#pragma unroll
      for (int nd = 0; nd < 2; nd++)
        YA[rg * YAS + 768 + head * 32 + nd * 16 + fl] = f2bf(oacc[i2][nd][r] * g);
    }
  }
}

// ---------------- host launch ----------------
extern "C" void kernel_launch(void* const* d_in, const int* in_sizes, int n_in,
                              void* d_out, int out_size, void* d_ws, size_t ws_size,
                              hipStream_t stream) {
  const float* x        = (const float*)d_in[0];
  const float* norm1_w  = (const float*)d_in[1];
  const float* norm1_b  = (const float*)d_in[2];
  const float* W_in     = (const float*)d_in[3];
  const float* conv_w   = (const float*)d_in[4];
  const float* conv_b   = (const float*)d_in[5];
  const float* dt_bias  = (const float*)d_in[6];
  const float* A_log    = (const float*)d_in[7];
  const float* Dp       = (const float*)d_in[8];
  const float* mnorm_w  = (const float*)d_in[9];
  const float* W_out    = (const float*)d_in[10];
  const float* qkv_w    = (const float*)d_in[11];
  const float* qkv_b    = (const float*)d_in[12];
  const float* gate_w   = (const float*)d_in[13];
  const float* gate_b   = (const float*)d_in[14];
  const float* proj_w   = (const float*)d_in[15];
  const float* proj_b   = (const float*)d_in[16];
  const float* fusion_w = (const float*)d_in[17];
  const float* fusion_b = (const float*)d_in[18];
  const float* norm2_w  = (const float*)d_in[19];
  const float* norm2_b  = (const float*)d_in[20];
  const float* fc1_w    = (const float*)d_in[21];
  const float* fc1_b    = (const float*)d_in[22];
  const float* fc2_w    = (const float*)d_in[23];
  const float* fc2_b    = (const float*)d_in[24];
  float* OUT = (float*)d_out;

  float* ws = (float*)d_ws;
  unsigned short* XNBF = (unsigned short*)ws;               // 25088x384 bf16 (4,816,896 fl)
  float* XCR  = ws + 4816896;                               // conv out bf16 25088x896 (11,239,424 fl)
  float* SCR  = XCR + 11239424;                             // ZX bf16 -> H fp32 -> z bf16 -> QKVbf -> M1bf (19,267,584 fl)
  float* YAR  = SCR + 19267584;                             // concat [Y | XA] bf16 25088x1152 (14,450,688 fl)
  unsigned short* WT = (unsigned short*)(YAR + 14450688);   // weights region (3,489,792 shorts)
  float* DT_ = (float*)(WT + 3489792);                      // 301,056
  float* DA_ = DT_ + 301056;                                // 301,056 (log-decay)
  float* G_  = DA_ + 301056;                                // 301,056
  float* QS_ = G_  + 301056;                                // 5,376 (need 4,704)
  float* CB_ = QS_ + 5376;                                  // 384 combined bias

  unsigned short* XCBF  = (unsigned short*)XCR;             // conv output bf16 [25088][896]
  unsigned short* ZXBF  = (unsigned short*)SCR;             // combined xBC+dt bf16 [25088][1024]
  float* H_ = SCR;                                          // 96*49*4096 = 19,267,584 fl
  unsigned short* ZBF   = (unsigned short*)SCR;             // z bf16 (after H consumed)
  unsigned short* QKVBF = (unsigned short*)SCR;
  unsigned short* M1BF  = (unsigned short*)SCR;
  unsigned short* YABF  = (unsigned short*)YAR;             // [25088][1152]

  unsigned short* wt_xbcdt = WT;             // 1024x384
  unsigned short* wt_z     = WT + 393216;    // 768x384
  unsigned short* wt_qkv   = WT + 688128;    // 1152x384
  unsigned short* wt_fc1   = WT + 1130496;   // 1536x384
  unsigned short* wt_fc2   = WT + 1720320;   // 384x1536
  unsigned short* wt_fus   = WT + 2310144;   // 384x768 (fusion_w^T)
  unsigned short* wob      = WT + 2605056;   // W_out plain bf16 [768][384]
  unsigned short* wpb      = WT + 2899968;   // W_proj plain bf16 [384][384]
  unsigned short* wt_comb  = WT + 3047424;   // combined [384][1152]

  // ---- weight prep ----
  wconv_kernel<<<dim3(12,  29), 256, 0, stream>>>(W_in + 768,  wt_xbcdt, 384, 908, DPROJ);
  wconv_kernel<<<dim3(12,  24), 256, 0, stream>>>(W_in,        wt_z,    384,  768, DPROJ);
  wconv_kernel<<<dim3(12,  36), 256, 0, stream>>>(qkv_w,       wt_qkv,  384, 1152, 1152);
  wconv_kernel<<<dim3(12,  48), 256, 0, stream>>>(fc1_w,       wt_fc1,  384, 1536, 1536);
  wconv_kernel<<<dim3(48,  12), 256, 0, stream>>>(fc2_w,       wt_fc2, 1536,  384, 384);
  wconv_kernel<<<dim3(24,  12), 256, 0, stream>>>(fusion_w,    wt_fus,  768,  384, 384);
  plainconv_kernel<<<(294912 + 255) / 256, 256, 0, stream>>>(W_out,  wob, 294912);
  plainconv_kernel<<<(147456 + 255) / 256, 256, 0, stream>>>(proj_w, wpb, 147456);
  // wt_comb[n][k]      = sum_j fusion_w[j][n]   * W_out[k][j]   (k in [0,768))
  gemm_bf<0, false, false, true><<<dim3(6, 3), 256, 0, stream>>>(
      wt_fus,       wob, wt_comb, nullptr, nullptr, 0, 384, 768, 384, 768, YAS, 0);
  // wt_comb[n][768+k2] = sum_j fusion_w[384+j][n] * W_proj[k2][j]
  gemm_bf<0, false, false, true><<<dim3(3, 3), 256, 0, stream>>>(
      wt_fus + 384, wpb, wt_comb, nullptr, nullptr, 0, 384, 384, 384, 768, YAS, 768);
  biascomb_kernel<<<2, 256, 0, stream>>>(fusion_w, fusion_b, proj_b, CB_);

  // ---- main flow ----
  ln_kernel<<<6272, 256, 0, stream>>>(x, norm1_w, norm1_b, XNBF);

  gemm_bf<0, false, false, true><<<dim3(8, 196), 256, 0, stream>>>(
      XNBF, wt_xbcdt, ZXBF, nullptr, nullptr, 0, NROWS, 908, CDIM, CDIM, ZXLD, 0);
  conv_bf_kernel<<<392, 256, 0, stream>>>(ZXBF, conv_w, conv_b, XCBF, ZXLD);
  dtprep_kernel<<<(NROWS * NHM + 255) / 256, 256, 0, stream>>>(ZXBF, dt_bias, A_log, DT_, DA_);

  mscan1_kernel<<<dim3(NCH, 96), 256, 0, stream>>>(XCBF, DT_, DA_, H_, QS_);
  scomb_kernel<<<dim3(96, 16), 64, 0, stream>>>(H_, QS_);
  mscan2_kernel<<<dim3(NCH, 96), 256, 0, stream>>>(XCBF, DT_, DA_, H_, Dp, YABF);

  gemm_bf<0, false, false, true><<<dim3(6, 196), 256, 0, stream>>>(
      XNBF, wt_z, ZBF, nullptr, nullptr, 0, NROWS, DIN, CDIM, CDIM, DIN, 0);
  gate_rms_kernel<<<6272, 256, 0, stream>>>(YABF, ZBF, mnorm_w);

  attgate_kernel<<<6272, 256, 0, stream>>>(XNBF, gate_w, gate_b, G_);

  gemm_bf<0, true, false, true><<<dim3(9, 196), 256, 0, stream>>>(
      XNBF, wt_qkv, QKVBF, qkv_b, nullptr, 0, NROWS, 3 * CDIM, CDIM, CDIM, 3 * CDIM, 0);
  attn_kernel<<<512 * NHA, 64, 0, stream>>>(QKVBF, G_, YABF);

  // merged out+proj+fusion: OUT = YA @ wt_comb + CB + x
  gemm_bf<0, true, true, false><<<dim3(3, 196), 256, 0, stream>>>(
      YABF, wt_comb, OUT, CB_, x, CDIM, NROWS, CDIM, YAS, YAS, CDIM, 0);

  ln_kernel<<<6272, 256, 0, stream>>>(OUT, norm2_w, norm2_b, XNBF);

  gemm_bf<1, true, false, true><<<dim3(12, 196), 256, 0, stream>>>(
      XNBF, wt_fc1, M1BF, fc1_b, nullptr, 0, NROWS, 4 * CDIM, CDIM, CDIM, 4 * CDIM, 0);
  gemm_bf<0, true, true, false><<<dim3(3, 196), 256, 0, stream>>>(
      M1BF, wt_fc2, OUT, fc2_b, OUT, CDIM, NROWS, CDIM, 4 * CDIM, 4 * CDIM, CDIM, 0);
}

// Round 10
// 642.529 us; speedup vs baseline: 1.0345x; 1.0168x over previous
//
#include <hip/hip_runtime.h>
#include <math.h>

static constexpr int L_SEQ  = 3136;
static constexpr int NBATCH = 8;
static constexpr int CDIM   = 384;
static constexpr int DIN    = 768;
static constexpr int NHM    = 12;
static constexpr int HDM    = 64;
static constexpr int DPROJ  = 1676;   // 2*768 + 2*64 + 12
static constexpr int CONVD  = 896;    // 768 + 128
static constexpr int NROWS  = NBATCH * L_SEQ; // 25088
static constexpr int NHA    = 12;
static constexpr int NCH    = 49;     // chunks per sequence
static constexpr int CHT    = 64;     // tokens per chunk (49*64 = 3136)
static constexpr int CTK    = 28;     // tokens per conv thread (3136/28 = 112)
static constexpr int ZXLD   = 1024;   // combined xBC+dt output stride (908 padded)
static constexpr int YAS    = 1152;   // concat [Y | XA] row stride

typedef __attribute__((ext_vector_type(8))) short short8;
typedef __attribute__((ext_vector_type(8))) unsigned short ushort8;
typedef __attribute__((ext_vector_type(4))) float f32x4;
typedef const unsigned int __attribute__((address_space(1)))* gua_t;
typedef unsigned int __attribute__((address_space(3)))* lua_t;

__device__ __forceinline__ float siluf(float x) { return x / (1.f + __expf(-x)); }
__device__ __forceinline__ unsigned short f2bf(float f) {
  unsigned int u = __float_as_uint(f);
  u += 0x7fff + ((u >> 16) & 1);
  return (unsigned short)(u >> 16);
}
__device__ __forceinline__ float bf2f(unsigned short h) {
  return __uint_as_float(((unsigned int)h) << 16);
}
// GELU via A&S 7.1.25 3-term erf (|err|<=2.5e-5, far below bf16 ulp)
__device__ __forceinline__ float geluf(float v) {
  float ax = fabsf(v) * 0.70710678118654752f;
  float t = __builtin_amdgcn_rcpf(fmaf(0.47047f, ax, 1.f));
  float p = t * fmaf(t, fmaf(t, 0.7478556f, -0.0958798f), 0.3480242f);
  float e = __expf(-ax * ax);
  float r = 1.f - p * e;
  float h = 0.5f * v;
  return fmaf(fabsf(h), r, h);
}
__device__ __forceinline__ unsigned int pk_bf16(float lo, float hi) {
  unsigned int d;
  asm("v_cvt_pk_bf16_f32 %0, %1, %2" : "=v"(d) : "v"(lo), "v"(hi));
  return d;
}

// ---------------- LayerNorm: one wave per row, C=384, bf16 out ----------------
__global__ __launch_bounds__(256) void ln_kernel(const float* __restrict__ in,
    const float* __restrict__ w, const float* __restrict__ b, unsigned short* __restrict__ out) {
  int wave = threadIdx.x >> 6, lane = threadIdx.x & 63;
  int row = blockIdx.x * 4 + wave;
  if (row >= NROWS) return;
  const float* r = in + (size_t)row * CDIM;
  float2 v[3];
  float s1 = 0.f, s2 = 0.f;
#pragma unroll
  for (int q = 0; q < 3; q++) {
    v[q] = *(const float2*)&r[q * 128 + lane * 2];
    s1 += v[q].x + v[q].y;
    s2 += v[q].x * v[q].x + v[q].y * v[q].y;
  }
#pragma unroll
  for (int o = 32; o > 0; o >>= 1) { s1 += __shfl_xor(s1, o, 64); s2 += __shfl_xor(s2, o, 64); }
  float mu = s1 * (1.f / 384.f);
  float var = s2 * (1.f / 384.f) - mu * mu;
  float rs = rsqrtf(var + 1e-5f);
  unsigned short* o = out + (size_t)row * CDIM;
#pragma unroll
  for (int q = 0; q < 3; q++) {
    int c = q * 128 + lane * 2;
    float2 wv = *(const float2*)&w[c];
    float2 bv = *(const float2*)&b[c];
    float ox = (v[q].x - mu) * rs * wv.x + bv.x;
    float oy = (v[q].y - mu) * rs * wv.y + bv.y;
    *(unsigned int*)&o[c] = pk_bf16(ox, oy);
  }
}

// ---------------- weight convert + transpose: W[K][N] fp32 -> WT[Np][K] bf16 ----------------
__global__ __launch_bounds__(256) void wconv_kernel(const float* __restrict__ W,
    unsigned short* __restrict__ WT, int K, int N, int ldw) {
  __shared__ float tile[32][33];
  int k0 = blockIdx.x * 32, n0 = blockIdx.y * 32;
  int tx = threadIdx.x & 31, ty = threadIdx.x >> 5;
#pragma unroll
  for (int j = 0; j < 4; j++) {
    int k = k0 + ty + j * 8;
    int n = n0 + tx;
    tile[ty + j * 8][tx] = (n < N) ? W[(size_t)k * ldw + n] : 0.f;
  }
  __syncthreads();
#pragma unroll
  for (int j = 0; j < 4; j++) {
    int n = n0 + ty + j * 8;
    int k = k0 + tx;
    WT[(size_t)n * K + k] = f2bf(tile[tx][ty + j * 8]);
  }
}

// ---------------- plain fp32 -> bf16 convert (no transpose) ----------------
__global__ void plainconv_kernel(const float* __restrict__ W, unsigned short* __restrict__ O, int n) {
  int i = blockIdx.x * 256 + threadIdx.x;
  if (i < n) O[i] = f2bf(W[i]);
}

// ---------------- combined bias: cb[n] = fusion_b[n] + sum_j proj_b[j]*fusion_w[384+j][n] ----------------
__global__ void biascomb_kernel(const float* __restrict__ fw, const float* __restrict__ fb,
    const float* __restrict__ pb, float* __restrict__ cb) {
  int n = blockIdx.x * 256 + threadIdx.x;
  if (n >= 384) return;
  float a = fb[n];
  for (int j = 0; j < 384; j++) a += pb[j] * fw[(size_t)(384 + j) * 384 + n];
  cb[n] = a;
}

// ---------------- bf16 MFMA GEMM: 3-buffer depth-2 counted-vmcnt pipeline,
// ---------------- slot-XOR LDS swizzle, XCD swizzle, transposed acc + swizzled LDS-bounce epilogue
// ---------------- R10: sched_barrier(0) REMOVED from the K-loop (m141: order-pinning defeats compiler pipelining)
template<int ACT, bool HASBIAS, bool HASRES, bool OUTBF>
__global__ __launch_bounds__(256, 4) void gemm_bf(
    const unsigned short* __restrict__ A, const unsigned short* __restrict__ WT,
    void* __restrict__ Cp, const float* __restrict__ bias,
    const float* __restrict__ res, int ldr,
    int M, int N, int K, int lda, int ldc, int coff)
{
  __shared__ unsigned short SMEM[24576];   // A bufs @ {0,4096,8192}, W bufs @ {12288,+4096,+8192}; reused as bounce
  int t = threadIdx.x;
  // XCD-aware bijective remap (m204)
  int gx = gridDim.x;
  int nwg = gx * gridDim.y;
  int orig = blockIdx.y * gx + blockIdx.x;
  int qq = nwg >> 3, rr = nwg & 7;
  int xcd = orig & 7, seq = orig >> 3;
  int wgid = (xcd < rr ? xcd * (qq + 1) : rr * (qq + 1) + (xcd - rr) * qq) + seq;
  int m0 = (wgid / gx) * 128, n0 = (wgid % gx) * 128;

  int lane = t & 63, w = t >> 6;
  int wr = (w >> 1) * 64, wc = (w & 1) * 64;
  int fl = lane & 15, kq = lane >> 4;
  int so = (kq ^ ((lane >> 1) & 3)) * 8;   // swizzled 16B slot for ds_read

  int srow = t >> 2, sq = t & 3;
  int q0 = sq ^ ((srow >> 1) & 3);
  const unsigned short* pA0 = A  + (size_t)(m0 + srow) * lda + q0 * 8;
  const unsigned short* pA1 = A  + (size_t)(m0 + 64 + srow) * lda + q0 * 8;
  const unsigned short* pW0 = WT + (size_t)(n0 + srow) * K + q0 * 8;
  const unsigned short* pW1 = WT + (size_t)(n0 + 64 + srow) * K + q0 * 8;

  f32x4 acc[4][4];     // transposed: acc[mi][ni] regs = n (kq*4+r), lanes = m (fl)
#pragma unroll
  for (int i = 0; i < 4; i++)
#pragma unroll
    for (int j = 0; j < 4; j++) acc[i][j] = (f32x4)0.f;

  auto STAGE = [&](int buf) {
    unsigned short* as = SMEM + buf * 4096;
    unsigned short* ws = SMEM + 12288 + buf * 4096;
    __builtin_amdgcn_global_load_lds((gua_t)pA0, (lua_t)as + t * 4, 16, 0, 0);
    __builtin_amdgcn_global_load_lds((gua_t)pA1, (lua_t)(as + 2048) + t * 4, 16, 0, 0);
    __builtin_amdgcn_global_load_lds((gua_t)pW0, (lua_t)ws + t * 4, 16, 0, 0);
    __builtin_amdgcn_global_load_lds((gua_t)pW1, (lua_t)(ws + 2048) + t * 4, 16, 0, 0);
    pA0 += 32; pA1 += 32; pW0 += 32; pW1 += 32;
  };

  int nk = K >> 5;               // all K here are >= 64, so nk >= 2
  STAGE(0);
  STAGE(1);
  int cb = 0, sb = 2;
  for (int ks = 0; ks < nk; ks++) {
    if (ks + 1 < nk) {
      asm volatile("s_waitcnt vmcnt(4)" ::: "memory");   // tile ks landed; tile ks+1 stays in flight
    } else {
      asm volatile("s_waitcnt vmcnt(0)" ::: "memory");
    }
    __builtin_amdgcn_s_barrier();
    asm volatile("" ::: "memory");
    if (ks + 2 < nk) {           // buffer sb's readers (tile ks-1) drained at the barrier above
      STAGE(sb);
      sb = sb == 2 ? 0 : sb + 1;
    }
    const unsigned short* as = SMEM + cb * 4096;
    const unsigned short* ws = SMEM + 12288 + cb * 4096;
    cb = cb == 2 ? 0 : cb + 1;
    short8 af[4], bfr[4];
#pragma unroll
    for (int mi = 0; mi < 4; mi++) af[mi] = *(const short8*)&as[(wr + mi * 16 + fl) * 32 + so];
#pragma unroll
    for (int ni = 0; ni < 4; ni++) bfr[ni] = *(const short8*)&ws[(wc + ni * 16 + fl) * 32 + so];
    // swapped operands: output rows = n (from W frag), cols = m (from A frag)
#pragma unroll
    for (int mi = 0; mi < 4; mi++)
#pragma unroll
      for (int ni = 0; ni < 4; ni++)
        acc[mi][ni] = __builtin_amdgcn_mfma_f32_16x16x32_bf16(bfr[ni], af[mi], acc[mi][ni], 0, 0, 0);
  }
  // epilogue: lane holds m = wr+mi*16+fl, n = wc+ni*16+kq*4+{0..3}
  if (OUTBF) {
    __syncthreads();   // reuse SMEM as 128x128 bf16 bounce tile (granule-XOR swizzled)
    float4 bv[4];
    if (HASBIAS) {
#pragma unroll
      for (int ni = 0; ni < 4; ni++) bv[ni] = *(const float4*)&bias[n0 + wc + ni * 16 + kq * 4];
    }
#pragma unroll
    for (int mi = 0; mi < 4; mi++) {
      int mloc = wr + mi * 16 + fl;
#pragma unroll
      for (int ni = 0; ni < 4; ni++) {
        float v0 = acc[mi][ni][0], v1 = acc[mi][ni][1];
        float v2 = acc[mi][ni][2], v3 = acc[mi][ni][3];
        if (HASBIAS) { v0 += bv[ni].x; v1 += bv[ni].y; v2 += bv[ni].z; v3 += bv[ni].w; }
        if (ACT == 1) { v0 = geluf(v0); v1 = geluf(v1); v2 = geluf(v2); v3 = geluf(v3); }
        int gidx = (wc >> 2) + ni * 4 + kq;          // 8B granule index in row (0..31)
        int gs = gidx ^ (mloc & 15);                 // bank-spread swizzle
        uint2 pk; pk.x = pk_bf16(v0, v1); pk.y = pk_bf16(v2, v3);
        *(uint2*)&SMEM[mloc * 128 + gs * 4] = pk;
      }
    }
    __syncthreads();
    unsigned short* outp = (unsigned short*)Cp + coff + n0;
#pragma unroll
    for (int it2 = 0; it2 < 16; it2++) {
      int gg = it2 * 256 + t;
      int row = gg >> 5, g = gg & 31;
      uint2 v = *(const uint2*)&SMEM[row * 128 + (g ^ (row & 15)) * 4];
      *(uint2*)&outp[(size_t)(m0 + row) * ldc + g * 4] = v;
    }
  } else {
    int rbase = kq * 4;
    float* outp = (float*)Cp + coff;
#pragma unroll
    for (int mi = 0; mi < 4; mi++) {
      int m = m0 + wr + mi * 16 + fl;
      float* rowp = outp + (size_t)m * ldc + n0;
#pragma unroll
      for (int ni = 0; ni < 4; ni++) {
        int nb = wc + ni * 16 + rbase;
        float4 v;
        v.x = acc[mi][ni][0]; v.y = acc[mi][ni][1];
        v.z = acc[mi][ni][2]; v.w = acc[mi][ni][3];
        if (HASBIAS) {
          float4 bvv = *(const float4*)&bias[n0 + nb];
          v.x += bvv.x; v.y += bvv.y; v.z += bvv.z; v.w += bvv.w;
        }
        if (ACT == 1) { v.x = geluf(v.x); v.y = geluf(v.y); v.z = geluf(v.z); v.w = geluf(v.w); }
        if (HASRES) {
          float4 rv = *(const float4*)&res[(size_t)m * ldr + n0 + nb];
          v.x += rv.x; v.y += rv.y; v.z += rv.z; v.w += rv.w;
        }
        *(float4*)&rowp[nb] = v;
      }
    }
  }
}

// ---------------- dt prep: read bf16 dt slice of combined ZX; DA holds LOG-decay ----------------
__global__ void dtprep_kernel(const unsigned short* __restrict__ ZX, const float* __restrict__ dt_bias,
    const float* __restrict__ A_log, float* __restrict__ DT, float* __restrict__ DA) {
  int idx = blockIdx.x * blockDim.x + threadIdx.x;
  if (idx >= NROWS * NHM) return;
  int h = idx % NHM;
  int row = idx / NHM;
  float v = bf2f(ZX[(size_t)row * ZXLD + 896 + h]) + dt_bias[h];
  float sp = (v > 20.f) ? v : log1pf(expf(v));
  DT[idx] = sp;
  DA[idx] = -expf(A_log[h]) * sp;   // log of decay (<= 0)
}

// ---------------- depthwise causal conv (k=4) + bias + silu; bf16 in/out, reg shift history ----------------
__global__ __launch_bounds__(256) void conv_bf_kernel(const unsigned short* __restrict__ xbc,
    const float* __restrict__ cw, const float* __restrict__ cb, unsigned short* __restrict__ XC,
    int ldin) {
  int t = blockIdx.x * 256 + threadIdx.x;
  int c8 = t % 112;                 // 8-channel group within row (112*8 = 896)
  int rg = t / 112;                 // b * 112 + lchunk
  int b = rg / 112, lc = rg % 112;
  int l0 = lc * CTK;
  int c0 = c8 * 8;
  float w0[8], w1[8], w2[8], w3[8], bq[8];
#pragma unroll
  for (int i = 0; i < 8; i++) {
    bq[i] = cb[c0 + i];
    float4 w4 = *(const float4*)&cw[(c0 + i) * 4];
    w0[i] = w4.x; w1[i] = w4.y; w2[i] = w4.z; w3[i] = w4.w;
  }
  const unsigned short* base = xbc + (size_t)b * L_SEQ * ldin + c0;
  unsigned short* obase = XC + (size_t)b * L_SEQ * CONVD + c0;
  ushort8 h0 = (ushort8)0, h1 = (ushort8)0, h2 = (ushort8)0;
  if (l0 >= 3) {
    h0 = *(const ushort8*)&base[(size_t)(l0 - 3) * ldin];
    h1 = *(const ushort8*)&base[(size_t)(l0 - 2) * ldin];
    h2 = *(const ushort8*)&base[(size_t)(l0 - 1) * ldin];
  }
  for (int i = 0; i < CTK; i++) {
    ushort8 cur = *(const ushort8*)&base[(size_t)(l0 + i) * ldin];
    ushort8 ov;
#pragma unroll
    for (int q = 0; q < 8; q++) {
      float acc = bq[q] + w0[q] * bf2f(h0[q]) + w1[q] * bf2f(h1[q])
                + w2[q] * bf2f(h2[q]) + w3[q] * bf2f(cur[q]);
      ov[q] = f2bf(siluf(acc));
    }
    *(ushort8*)&obase[(size_t)(l0 + i) * CONVD] = ov;
    h0 = h1; h1 = h2; h2 = cur;
  }
}

// ---------------- chunked SSD scan pass 1 (MFMA): G^T[p][n] = sum_j X[j][p] * (B[j][n]*w[j]) ----------------
__global__ __launch_bounds__(256) void mscan1_kernel(const unsigned short* __restrict__ XC,
    const float* __restrict__ dtp, const float* __restrict__ dta,
    float* __restrict__ H, float* __restrict__ QS) {
  __shared__ unsigned short Xt[64 * 72];   // X^T [p][j]
  __shared__ unsigned short Bt[64 * 72];   // (B*w)^T [n][j]
  __shared__ float lcs[64];
  __shared__ float wss[64];
  int ch = blockIdx.x, bh = blockIdx.y;
  int b = bh / NHM, head = bh - b * NHM;
  int t = threadIdx.x;
  int l0 = ch * CHT;
  const unsigned short* xcb = XC + ((size_t)b * L_SEQ + l0) * CONVD;
  if (t < 64) {
    size_t ro = ((size_t)b * L_SEQ + l0 + t) * NHM + head;
    float s = dta[ro];
#pragma unroll
    for (int o = 1; o < 64; o <<= 1) {
      float u = __shfl_up(s, o, 64);
      if (t >= o) s += u;
    }
    float lc63 = __shfl(s, 63, 64);
    lcs[t] = s;
    wss[t] = dtp[ro] * __expf(lc63 - s);
    if (t == 63) QS[bh * NCH + ch] = __expf(s);
  }
  __syncthreads();
#pragma unroll
  for (int it = 0; it < 16; it++) {
    int e = it * 256 + t;
    int j = e >> 6, cc = e & 63;
    const unsigned short* rowp = xcb + (size_t)j * CONVD;
    Xt[cc * 72 + j] = rowp[head * HDM + cc];
    Bt[cc * 72 + j] = f2bf(bf2f(rowp[768 + cc]) * wss[j]);
  }
  __syncthreads();
  int lane = t & 63, w = t >> 6;
  int wr = (w >> 1) * 32, wc = (w & 1) * 32;
  int fl = lane & 15, kq = lane >> 4;
  f32x4 acc[2][2];
#pragma unroll
  for (int i = 0; i < 2; i++)
#pragma unroll
    for (int j = 0; j < 2; j++) acc[i][j] = (f32x4)0.f;
#pragma unroll
  for (int kk = 0; kk < 2; kk++) {
    short8 af[2], bfr[2];
#pragma unroll
    for (int mi = 0; mi < 2; mi++)
      af[mi] = *(const short8*)&Xt[(wr + mi * 16 + fl) * 72 + kk * 32 + kq * 8];
#pragma unroll
    for (int ni = 0; ni < 2; ni++)
      bfr[ni] = *(const short8*)&Bt[(wc + ni * 16 + fl) * 72 + kk * 32 + kq * 8];
#pragma unroll
    for (int mi = 0; mi < 2; mi++)
#pragma unroll
      for (int ni = 0; ni < 2; ni++)
        acc[mi][ni] = __builtin_amdgcn_mfma_f32_16x16x32_bf16(af[mi], bfr[ni], acc[mi][ni], 0, 0, 0);
  }
  float* Hp = H + ((size_t)bh * NCH + ch) * 4096;
  int rbase = kq * 4, cl = fl;
#pragma unroll
  for (int mi = 0; mi < 2; mi++)
#pragma unroll
    for (int ni = 0; ni < 2; ni++)
#pragma unroll
      for (int r = 0; r < 4; r++)
        Hp[(size_t)(wr + mi * 16 + rbase + r) * 64 + wc + ni * 16 + cl] = acc[mi][ni][r];
}

// ---------------- scan combine (exclusive prefix over chunks) ----------------
__global__ __launch_bounds__(64) void scomb_kernel(float* __restrict__ H,
    const float* __restrict__ QS) {
  int bh = blockIdx.x;
  int e = (blockIdx.y * 64 + threadIdx.x) * 4;
  float4 cur = make_float4(0.f, 0.f, 0.f, 0.f);
  for (int s = 0; s < NCH; s++) {
    float* Hp = H + ((size_t)bh * NCH + s) * 4096 + e;
    float q = QS[bh * NCH + s];
    float4 tmp = *(float4*)Hp;
    *(float4*)Hp = cur;
    cur.x = q * cur.x + tmp.x;
    cur.y = q * cur.y + tmp.y;
    cur.z = q * cur.z + tmp.z;
    cur.w = q * cur.w + tmp.w;
  }
}

// ---------------- chunked SSD scan pass 2 (MFMA); writes Y into YA cols 0..767 ----------------
__global__ __launch_bounds__(256) void mscan2_kernel(const unsigned short* __restrict__ XC,
    const float* __restrict__ dtp, const float* __restrict__ dta,
    const float* __restrict__ H, const float* __restrict__ Dp,
    unsigned short* __restrict__ Ybf) {
  __shared__ unsigned short Cs[64 * 72];   // C [i][n] (later scaled by exp(lc[i]))
  __shared__ unsigned short Bs[64 * 72];   // B [j][n]
  __shared__ unsigned short Xt[64 * 72];   // X^T [p][j]
  __shared__ unsigned short Hs[64 * 72];   // Hprev [p][n]
  __shared__ unsigned short Ss[64 * 72];   // S [i][j] masked+scaled
  __shared__ float lcs[64];
  __shared__ float dts[64];
  int ch = blockIdx.x, bh = blockIdx.y;
  int b = bh / NHM, head = bh - b * NHM;
  int t = threadIdx.x;
  int l0 = ch * CHT;
  const unsigned short* xcb = XC + ((size_t)b * L_SEQ + l0) * CONVD;
  const float* Hg = H + ((size_t)bh * NCH + ch) * 4096;
  if (t < 64) {
    size_t ro = ((size_t)b * L_SEQ + l0 + t) * NHM + head;
    float s = dta[ro];
#pragma unroll
    for (int o = 1; o < 64; o <<= 1) {
      float u = __shfl_up(s, o, 64);
      if (t >= o) s += u;
    }
    lcs[t] = s;
    dts[t] = dtp[ro];
  }
#pragma unroll
  for (int it = 0; it < 16; it++) {
    int e = it * 256 + t;
    int j = e >> 6, cc = e & 63;
    const unsigned short* rowp = xcb + (size_t)j * CONVD;
    Xt[cc * 72 + j] = rowp[head * HDM + cc];
    Bs[j * 72 + cc] = rowp[768 + cc];
    Cs[j * 72 + cc] = rowp[832 + cc];
    Hs[j * 72 + cc] = f2bf(Hg[e]);          // Hg layout is [p][n]
  }
  __syncthreads();
  int lane = t & 63, w = t >> 6;
  int wr = (w >> 1) * 32, wc = (w & 1) * 32;
  int fl = lane & 15, kq = lane >> 4;
  int rbase = kq * 4, cl = fl;
  // ---- product 1: S_raw = C @ B^T (contract over n) ----
  f32x4 sacc[2][2];
#pragma unroll
  for (int i = 0; i < 2; i++)
#pragma unroll
    for (int j = 0; j < 2; j++) sacc[i][j] = (f32x4)0.f;
#pragma unroll
  for (int kk = 0; kk < 2; kk++) {
    short8 af[2], bfr[2];
#pragma unroll
    for (int mi = 0; mi < 2; mi++)
      af[mi] = *(const short8*)&Cs[(wr + mi * 16 + fl) * 72 + kk * 32 + kq * 8];
#pragma unroll
    for (int ni = 0; ni < 2; ni++)
      bfr[ni] = *(const short8*)&Bs[(wc + ni * 16 + fl) * 72 + kk * 32 + kq * 8];
#pragma unroll
    for (int mi = 0; mi < 2; mi++)
#pragma unroll
      for (int ni = 0; ni < 2; ni++)
        sacc[mi][ni] = __builtin_amdgcn_mfma_f32_16x16x32_bf16(af[mi], bfr[ni], sacc[mi][ni], 0, 0, 0);
  }
  __syncthreads();   // everyone done reading Cs/Bs fragments
  // ---- build S (mask j<=i, scale by dt[j]*exp(lc[i]-lc[j])); rescale C in place by exp(lc[i]) ----
#pragma unroll
  for (int mi = 0; mi < 2; mi++)
#pragma unroll
    for (int ni = 0; ni < 2; ni++)
#pragma unroll
      for (int r = 0; r < 4; r++) {
        int i = wr + mi * 16 + rbase + r;
        int j = wc + ni * 16 + cl;
        float v = (j <= i) ? sacc[mi][ni][r] * dts[j] * __expf(lcs[i] - lcs[j]) : 0.f;
        Ss[i * 72 + j] = f2bf(v);
      }
#pragma unroll
  for (int it = 0; it < 16; it++) {
    int e = it * 256 + t;
    int i = e >> 6, n = e & 63;
    float cv = bf2f(Cs[i * 72 + n]) * __expf(lcs[i]);
    Cs[i * 72 + n] = f2bf(cv);
  }
  __syncthreads();
  // ---- products 2+3 accumulated: Y = S @ X  +  C'' @ Hprev^T(layout) ----
  f32x4 yacc[2][2];
#pragma unroll
  for (int i = 0; i < 2; i++)
#pragma unroll
    for (int j = 0; j < 2; j++) yacc[i][j] = (f32x4)0.f;
#pragma unroll
  for (int kk = 0; kk < 2; kk++) {
    short8 af[2], bfr[2];
#pragma unroll
    for (int mi = 0; mi < 2; mi++)
      af[mi] = *(const short8*)&Ss[(wr + mi * 16 + fl) * 72 + kk * 32 + kq * 8];
#pragma unroll
    for (int ni = 0; ni < 2; ni++)
      bfr[ni] = *(const short8*)&Xt[(wc + ni * 16 + fl) * 72 + kk * 32 + kq * 8];
#pragma unroll
    for (int mi = 0; mi < 2; mi++)
#pragma unroll
      for (int ni = 0; ni < 2; ni++)
        yacc[mi][ni] = __builtin_amdgcn_mfma_f32_16x16x32_bf16(af[mi], bfr[ni], yacc[mi][ni], 0, 0, 0);
  }
#pragma unroll
  for (int kk = 0; kk < 2; kk++) {
    short8 af[2], bfr[2];
#pragma unroll
    for (int mi = 0; mi < 2; mi++)
      af[mi] = *(const short8*)&Cs[(wr + mi * 16 + fl) * 72 + kk * 32 + kq * 8];
#pragma unroll
    for (int ni = 0; ni < 2; ni++)
      bfr[ni] = *(const short8*)&Hs[(wc + ni * 16 + fl) * 72 + kk * 32 + kq * 8];
#pragma unroll
    for (int mi = 0; mi < 2; mi++)
#pragma unroll
      for (int ni = 0; ni < 2; ni++)
        yacc[mi][ni] = __builtin_amdgcn_mfma_f32_16x16x32_bf16(af[mi], bfr[ni], yacc[mi][ni], 0, 0, 0);
  }
  // ---- epilogue: + D * x, write bf16 into YA (stride YAS) ----
  float Dh = Dp[head];
  unsigned short* yb = Ybf + ((size_t)b * L_SEQ + l0) * YAS + head * HDM;
#pragma unroll
  for (int mi = 0; mi < 2; mi++)
#pragma unroll
    for (int ni = 0; ni < 2; ni++)
#pragma unroll
      for (int r = 0; r < 4; r++) {
        int i = wr + mi * 16 + rbase + r;
        int p = wc + ni * 16 + cl;
        float xval = bf2f(Xt[p * 72 + i]);
        yb[(size_t)i * YAS + p] = f2bf(yacc[mi][ni][r] + Dh * xval);
      }
}

// ---------------- gated RMS norm in-place on YA cols 0..767 (bf16 y, bf16 z) ----------------
__global__ __launch_bounds__(256) void gate_rms_kernel(unsigned short* __restrict__ Y,
    const unsigned short* __restrict__ Z, const float* __restrict__ mw) {
  int wave = threadIdx.x >> 6, lane = threadIdx.x & 63;
  int row = blockIdx.x * 4 + wave;
  if (row >= NROWS) return;
  unsigned short* y = Y + (size_t)row * YAS;
  const unsigned short* z = Z + (size_t)row * DIN;
  float g[12];
  float ss = 0.f;
#pragma unroll
  for (int q = 0; q < 3; q++) {
    int c = q * 256 + lane * 4;
    uint2 yu = *(const uint2*)&y[c];
    uint2 zu = *(const uint2*)&z[c];
    float y0 = bf2f((unsigned short)(yu.x & 0xffff));
    float y1 = bf2f((unsigned short)(yu.x >> 16));
    float y2 = bf2f((unsigned short)(yu.y & 0xffff));
    float y3 = bf2f((unsigned short)(yu.y >> 16));
    float z0 = bf2f((unsigned short)(zu.x & 0xffff));
    float z1 = bf2f((unsigned short)(zu.x >> 16));
    float z2 = bf2f((unsigned short)(zu.y & 0xffff));
    float z3 = bf2f((unsigned short)(zu.y >> 16));
    float g0 = y0 * siluf(z0), g1 = y1 * siluf(z1);
    float g2 = y2 * siluf(z2), g3 = y3 * siluf(z3);
    ss += g0 * g0 + g1 * g1 + g2 * g2 + g3 * g3;
    g[q * 4 + 0] = g0; g[q * 4 + 1] = g1; g[q * 4 + 2] = g2; g[q * 4 + 3] = g3;
  }
#pragma unroll
  for (int o = 32; o > 0; o >>= 1) ss += __shfl_xor(ss, o, 64);
  float rs = rsqrtf(ss * (1.f / 768.f) + 1e-5f);
#pragma unroll
  for (int q = 0; q < 3; q++) {
    int c = q * 256 + lane * 4;
    float4 m = *(const float4*)&mw[c];
    uint2 pk;
    pk.x = pk_bf16(g[q*4+0] * rs * m.x, g[q*4+1] * rs * m.y);
    pk.y = pk_bf16(g[q*4+2] * rs * m.z, g[q*4+3] * rs * m.w);
    *(uint2*)&y[c] = pk;
  }
}

// ---------------- attention gate ----------------
__global__ __launch_bounds__(256) void attgate_kernel(const unsigned short* __restrict__ XN,
    const float* __restrict__ gw, const float* __restrict__ gb, float* __restrict__ G) {
  int wave = threadIdx.x >> 6, lane = threadIdx.x & 63;
  int row = blockIdx.x * 4 + wave;
  if (row >= NROWS) return;
  const unsigned short* x = XN + (size_t)row * CDIM;
  float acc[12] = {};
#pragma unroll
  for (int q = 0; q < 6; q++) {
    int k = q * 64 + lane;
    float xv = bf2f(x[k]);
    const float* wr = gw + (size_t)k * 12;
    float4 w0 = *(const float4*)&wr[0];
    float4 w1 = *(const float4*)&wr[4];
    float4 w2 = *(const float4*)&wr[8];
    acc[0] += xv * w0.x; acc[1] += xv * w0.y; acc[2]  += xv * w0.z; acc[3]  += xv * w0.w;
    acc[4] += xv * w1.x; acc[5] += xv * w1.y; acc[6]  += xv * w1.z; acc[7]  += xv * w1.w;
    acc[8] += xv * w2.x; acc[9] += xv * w2.y; acc[10] += xv * w2.z; acc[11] += xv * w2.w;
  }
#pragma unroll
  for (int h = 0; h < 12; h++)
#pragma unroll
    for (int o = 32; o > 0; o >>= 1) acc[h] += __shfl_xor(acc[h], o, 64);
  if (lane == 0) {
#pragma unroll
    for (int h = 0; h < 12; h++) {
      float v = acc[h] + gb[h];
      G[(size_t)row * 12 + h] = 1.f / (1.f + expf(-v));
    }
  }
}

// ---------------- windowed attention via MFMA; writes gated out into YA cols 768..1151 ----------------
__global__ __launch_bounds__(64) void attn_kernel(const unsigned short* __restrict__ QKV,
    const float* __restrict__ G, unsigned short* __restrict__ YA) {
  __shared__ unsigned short Pl[64 * 72];   // P [i][j], row stride 72 (144B)
  __shared__ unsigned short Vt[32 * 72];   // V^T [d][j], slot-swizzled: slot' = (j>>3) ^ (d>>3)
  int blk = blockIdx.x;
  int head = blk % NHA;
  int win = blk / NHA;
  int b = win >> 6;
  int wrw = win & 63;
  int wy = wrw >> 3, wx = wrw & 7;
  int lane = threadIdx.x;
  int fl = lane & 15, kq = lane >> 4;
  const float scale = 0.17677669529663688f;
  size_t bbase = (size_t)b * L_SEQ;
  const unsigned short* qb = QKV + head * 32;

  short8 aq[4], bk[4];
#pragma unroll
  for (int ti = 0; ti < 4; ti++) {
    int tok = ti * 16 + fl; if (tok > 48) tok = 48;
    int iy = tok / 7, ix = tok - iy * 7;
    size_t r = bbase + (size_t)(wy * 7 + iy) * 56 + wx * 7 + ix;
    aq[ti] = *(const short8*)&qb[r * 1152 + kq * 8];
    bk[ti] = *(const short8*)&qb[r * 1152 + 384 + kq * 8];
  }
#pragma unroll
  for (int it = 0; it < 4; it++) {
    int j = (lane >> 2) + it * 16;
    int dc = (lane & 3) * 8;
    ushort8 v8 = (ushort8)0;
    if (j <= 48) {
      int iy = j / 7, ix = j - iy * 7;
      size_t r = bbase + (size_t)(wy * 7 + iy) * 56 + wx * 7 + ix;
      v8 = *(const ushort8*)&qb[r * 1152 + 768 + dc];
    }
#pragma unroll
    for (int q2 = 0; q2 < 8; q2++) {
      int d = dc + q2;
      Vt[d * 72 + (((j >> 3) ^ (d >> 3)) << 3) + (j & 7)] = v8[q2];
    }
  }
  f32x4 sacc[4][4];
#pragma unroll
  for (int tj = 0; tj < 4; tj++)
#pragma unroll
    for (int ti = 0; ti < 4; ti++)
      sacc[tj][ti] = __builtin_amdgcn_mfma_f32_16x16x32_bf16(bk[tj], aq[ti], (f32x4)0.f, 0, 0, 0);
#pragma unroll
  for (int ti = 0; ti < 4; ti++) {
    float mx = -1e30f;
#pragma unroll
    for (int tj = 0; tj < 4; tj++)
#pragma unroll
      for (int r = 0; r < 4; r++) {
        int j = tj * 16 + kq * 4 + r;
        float v = (j < 49) ? sacc[tj][ti][r] * scale : -1e30f;
        sacc[tj][ti][r] = v;
        mx = fmaxf(mx, v);
      }
    mx = fmaxf(mx, __shfl_xor(mx, 16, 64));
    mx = fmaxf(mx, __shfl_xor(mx, 32, 64));
    float sum = 0.f;
#pragma unroll
    for (int tj = 0; tj < 4; tj++)
#pragma unroll
      for (int r = 0; r < 4; r++) {
        float e = __expf(sacc[tj][ti][r] - mx);
        sacc[tj][ti][r] = e;
        sum += e;
      }
    sum += __shfl_xor(sum, 16, 64);
    sum += __shfl_xor(sum, 32, 64);
    float inv = 1.f / sum;
    int i = ti * 16 + fl;
#pragma unroll
    for (int tj = 0; tj < 4; tj++)
#pragma unroll
      for (int r = 0; r < 4; r++) {
        int j = tj * 16 + kq * 4 + r;
        Pl[i * 72 + j] = f2bf(sacc[tj][ti][r] * inv);
      }
  }
  f32x4 oacc[4][2];
#pragma unroll
  for (int i2 = 0; i2 < 4; i2++)
#pragma unroll
    for (int nd = 0; nd < 2; nd++) oacc[i2][nd] = (f32x4)0.f;
#pragma unroll
  for (int kk = 0; kk < 2; kk++) {
    short8 ap[4], bv[2];
#pragma unroll
    for (int i2 = 0; i2 < 4; i2++)
      ap[i2] = *(const short8*)&Pl[(i2 * 16 + fl) * 72 + kk * 32 + kq * 8];
#pragma unroll
    for (int nd = 0; nd < 2; nd++) {
      int d = nd * 16 + fl;
      bv[nd] = *(const short8*)&Vt[d * 72 + (((kk * 4 + kq) ^ (d >> 3)) << 3)];
    }
#pragma unroll
    for (int i2 = 0; i2 < 4; i2++)
#pragma unroll
      for (int nd = 0; nd < 2; nd++)
        oacc[i2][nd] = __builtin_amdgcn_mfma_f32_16x16x32_bf16(ap[i2], bv[nd], oacc[i2][nd], 0, 0, 0);
  }
#pragma unroll
  for (int i2 = 0; i2 < 4; i2++) {
#pragma unroll
    for (int r = 0; r < 4; r++) {
      int i = i2 * 16 + kq * 4 + r;
      if (i > 48) continue;
      int iy = i / 7, ix = i - iy * 7;
      size_t rg = bbase + (size_t)(wy * 7 + iy) * 56 + wx * 7 + ix;
      float g = G[rg * 12 + head];
#pragma unroll
      for (int nd = 0; nd < 2; nd++)
        YA[rg * YAS + 768 + head * 32 + nd * 16 + fl] = f2bf(oacc[i2][nd][r] * g);
    }
  }
}

// ---------------- host launch ----------------
extern "C" void kernel_launch(void* const* d_in, const int* in_sizes, int n_in,
                              void* d_out, int out_size, void* d_ws, size_t ws_size,
                              hipStream_t stream) {
  const float* x        = (const float*)d_in[0];
  const float* norm1_w  = (const float*)d_in[1];
  const float* norm1_b  = (const float*)d_in[2];
  const float* W_in     = (const float*)d_in[3];
  const float* conv_w   = (const float*)d_in[4];
  const float* conv_b   = (const float*)d_in[5];
  const float* dt_bias  = (const float*)d_in[6];
  const float* A_log    = (const float*)d_in[7];
  const float* Dp       = (const float*)d_in[8];
  const float* mnorm_w  = (const float*)d_in[9];
  const float* W_out    = (const float*)d_in[10];
  const float* qkv_w    = (const float*)d_in[11];
  const float* qkv_b    = (const float*)d_in[12];
  const float* gate_w   = (const float*)d_in[13];
  const float* gate_b   = (const float*)d_in[14];
  const float* proj_w   = (const float*)d_in[15];
  const float* proj_b   = (const float*)d_in[16];
  const float* fusion_w = (const float*)d_in[17];
  const float* fusion_b = (const float*)d_in[18];
  const float* norm2_w  = (const float*)d_in[19];
  const float* norm2_b  = (const float*)d_in[20];
  const float* fc1_w    = (const float*)d_in[21];
  const float* fc1_b    = (const float*)d_in[22];
  const float* fc2_w    = (const float*)d_in[23];
  const float* fc2_b    = (const float*)d_in[24];
  float* OUT = (float*)d_out;

  float* ws = (float*)d_ws;
  unsigned short* XNBF = (unsigned short*)ws;               // 25088x384 bf16 (4,816,896 fl)
  float* XCR  = ws + 4816896;                               // conv out bf16 25088x896 (11,239,424 fl)
  float* SCR  = XCR + 11239424;                             // ZX bf16 -> H fp32 -> z bf16 -> QKVbf -> M1bf (19,267,584 fl)
  float* YAR  = SCR + 19267584;                             // concat [Y | XA] bf16 25088x1152 (14,450,688 fl)
  unsigned short* WT = (unsigned short*)(YAR + 14450688);   // weights region (3,489,792 shorts)
  float* DT_ = (float*)(WT + 3489792);                      // 301,056
  float* DA_ = DT_ + 301056;                                // 301,056 (log-decay)
  float* G_  = DA_ + 301056;                                // 301,056
  float* QS_ = G_  + 301056;                                // 5,376 (need 4,704)
  float* CB_ = QS_ + 5376;                                  // 384 combined bias

  unsigned short* XCBF  = (unsigned short*)XCR;             // conv output bf16 [25088][896]
  unsigned short* ZXBF  = (unsigned short*)SCR;             // combined xBC+dt bf16 [25088][1024]
  float* H_ = SCR;                                          // 96*49*4096 = 19,267,584 fl
  unsigned short* ZBF   = (unsigned short*)SCR;             // z bf16 (after H consumed)
  unsigned short* QKVBF = (unsigned short*)SCR;
  unsigned short* M1BF  = (unsigned short*)SCR;
  unsigned short* YABF  = (unsigned short*)YAR;             // [25088][1152]

  unsigned short* wt_xbcdt = WT;             // 1024x384
  unsigned short* wt_z     = WT + 393216;    // 768x384
  unsigned short* wt_qkv   = WT + 688128;    // 1152x384
  unsigned short* wt_fc1   = WT + 1130496;   // 1536x384
  unsigned short* wt_fc2   = WT + 1720320;   // 384x1536
  unsigned short* wt_fus   = WT + 2310144;   // 384x768 (fusion_w^T)
  unsigned short* wob      = WT + 2605056;   // W_out plain bf16 [768][384]
  unsigned short* wpb      = WT + 2899968;   // W_proj plain bf16 [384][384]
  unsigned short* wt_comb  = WT + 3047424;   // combined [384][1152]

  // ---- weight prep ----
  wconv_kernel<<<dim3(12,  29), 256, 0, stream>>>(W_in + 768,  wt_xbcdt, 384, 908, DPROJ);
  wconv_kernel<<<dim3(12,  24), 256, 0, stream>>>(W_in,        wt_z,    384,  768, DPROJ);
  wconv_kernel<<<dim3(12,  36), 256, 0, stream>>>(qkv_w,       wt_qkv,  384, 1152, 1152);
  wconv_kernel<<<dim3(12,  48), 256, 0, stream>>>(fc1_w,       wt_fc1,  384, 1536, 1536);
  wconv_kernel<<<dim3(48,  12), 256, 0, stream>>>(fc2_w,       wt_fc2, 1536,  384, 384);
  wconv_kernel<<<dim3(24,  12), 256, 0, stream>>>(fusion_w,    wt_fus,  768,  384, 384);
  plainconv_kernel<<<(294912 + 255) / 256, 256, 0, stream>>>(W_out,  wob, 294912);
  plainconv_kernel<<<(147456 + 255) / 256, 256, 0, stream>>>(proj_w, wpb, 147456);
  gemm_bf<0, false, false, true><<<dim3(6, 3), 256, 0, stream>>>(
      wt_fus,       wob, wt_comb, nullptr, nullptr, 0, 384, 768, 384, 768, YAS, 0);
  gemm_bf<0, false, false, true><<<dim3(3, 3), 256, 0, stream>>>(
      wt_fus + 384, wpb, wt_comb, nullptr, nullptr, 0, 384, 384, 384, 768, YAS, 768);
  biascomb_kernel<<<2, 256, 0, stream>>>(fusion_w, fusion_b, proj_b, CB_);

  // ---- main flow ----
  ln_kernel<<<6272, 256, 0, stream>>>(x, norm1_w, norm1_b, XNBF);

  gemm_bf<0, false, false, true><<<dim3(8, 196), 256, 0, stream>>>(
      XNBF, wt_xbcdt, ZXBF, nullptr, nullptr, 0, NROWS, 908, CDIM, CDIM, ZXLD, 0);
  conv_bf_kernel<<<392, 256, 0, stream>>>(ZXBF, conv_w, conv_b, XCBF, ZXLD);
  dtprep_kernel<<<(NROWS * NHM + 255) / 256, 256, 0, stream>>>(ZXBF, dt_bias, A_log, DT_, DA_);

  mscan1_kernel<<<dim3(NCH, 96), 256, 0, stream>>>(XCBF, DT_, DA_, H_, QS_);
  scomb_kernel<<<dim3(96, 16), 64, 0, stream>>>(H_, QS_);
  mscan2_kernel<<<dim3(NCH, 96), 256, 0, stream>>>(XCBF, DT_, DA_, H_, Dp, YABF);

  gemm_bf<0, false, false, true><<<dim3(6, 196), 256, 0, stream>>>(
      XNBF, wt_z, ZBF, nullptr, nullptr, 0, NROWS, DIN, CDIM, CDIM, DIN, 0);
  gate_rms_kernel<<<6272, 256, 0, stream>>>(YABF, ZBF, mnorm_w);

  attgate_kernel<<<6272, 256, 0, stream>>>(XNBF, gate_w, gate_b, G_);

  gemm_bf<0, true, false, true><<<dim3(9, 196), 256, 0, stream>>>(
      XNBF, wt_qkv, QKVBF, qkv_b, nullptr, 0, NROWS, 3 * CDIM, CDIM, CDIM, 3 * CDIM, 0);
  attn_kernel<<<512 * NHA, 64, 0, stream>>>(QKVBF, G_, YABF);

  // merged out+proj+fusion: OUT = YA @ wt_comb + CB + x
  gemm_bf<0, true, true, false><<<dim3(3, 196), 256, 0, stream>>>(
      YABF, wt_comb, OUT, CB_, x, CDIM, NROWS, CDIM, YAS, YAS, CDIM, 0);

  ln_kernel<<<6272, 256, 0, stream>>>(OUT, norm2_w, norm2_b, XNBF);

  gemm_bf<1, true, false, true><<<dim3(12, 196), 256, 0, stream>>>(
      XNBF, wt_fc1, M1BF, fc1_b, nullptr, 0, NROWS, 4 * CDIM, CDIM, CDIM, 4 * CDIM, 0);
  gemm_bf<0, true, true, false><<<dim3(3, 196), 256, 0, stream>>>(
      M1BF, wt_fc2, OUT, fc2_b, OUT, CDIM, NROWS, CDIM, 4 * CDIM, 4 * CDIM, CDIM, 0);
}